// Round 10
// baseline (566.234 us; speedup 1.0000x reference)
//
#include <hip/hip_runtime.h>
#include <hip/hip_bf16.h>
#include <math.h>

#define SELU_ALPHA 1.6732632423543772f
#define SELU_SCALE 1.0507009873554805f

typedef __attribute__((ext_vector_type(8))) short bf16x8;
typedef __attribute__((ext_vector_type(4))) float f32x4;

__device__ __forceinline__ float selu_f(float x) {
    return x > 0.f ? SELU_SCALE * x : SELU_SCALE * SELU_ALPHA * (__expf(x) - 1.f);
}
__device__ __forceinline__ unsigned short f2bf(float f) {
    __hip_bfloat16 h = __float2bfloat16(f);
    return *(unsigned short*)&h;
}
__device__ __forceinline__ float bf2f(unsigned short u) {
    unsigned int x = ((unsigned int)u) << 16;
    float f; __builtin_memcpy(&f, &x, 4); return f;
}

constexpr int Bb = 256, Ll = 100, Hh = 1000, Ee = 100, Rr = 247, Tt = 15;
constexpr int KP_G = 1024;             // padded K for H-sized bf16 GEMMs
constexpr int KP_E = 128;              // padded K for E-sized x rows
constexpr int NCP = 3072;              // packed gate cols: 64 groups x 48 (r16|z16|n16)
constexpr int OUTW = Rr + 1 + Ll + 1;  // 349

// map packed col n' -> (part, j).  g=n'/48, rem=n'%48, part=rem/16, c=rem%16, j=g*16+c
__device__ __forceinline__ void unpack_col(int np, int& part, int& j) {
    int g = np / 48, rem = np % 48;
    part = rem >> 4;
    j = g * 16 + (rem & 15);
}

// ======== merged: attention (blocks 0..3071) + ALL weight packing ===========
// attn: id = b*12 + ch; ch 0..3 enc (chunk 25), 4..11 conv (chunk 31).
// Barrier-free per-wave rows; softmax via fixed shift exp(s-8) (scores |s|<~8).
__launch_bounds__(256)
__global__ void attn_pack(const float* __restrict__ enc, const float* __restrict__ conv,
                          const float* __restrict__ Wb,
                          float* __restrict__ part_ss, float* __restrict__ part_ctx,
                          const float* __restrict__ W_hh, const float* __restrict__ W_ih,
                          const float* __restrict__ W_pred, const float* __restrict__ W_fuse,
                          const float* __restrict__ h0, const float* __restrict__ b_hh,
                          const float* __restrict__ b_ih, const float* __restrict__ b_pred,
                          const float* __restrict__ b_eos, const float* __restrict__ W_eos,
                          const float* __restrict__ b_fuse,
                          unsigned short* __restrict__ Wp, unsigned short* __restrict__ Wihpb,
                          unsigned short* __restrict__ Wheads, unsigned short* __restrict__ Wfb,
                          unsigned short* __restrict__ h0b, float* __restrict__ h0f,
                          float* __restrict__ bhhp, float* __restrict__ bihp,
                          float* __restrict__ bias384, float* __restrict__ bfuse128) {
    __shared__ float4 sbuf4[4 * 256];     // attn: per-wave ctx partials (16 KB)
    __shared__ float sredA[4];
    int id = blockIdx.x, tid = threadIdx.x;
    int lane = tid & 63, wv = tid >> 6;
    if (id < 3072) {
        // ---------------- attention ----------------
        int b = id / 12, ch = id % 12;
        const float* mem; int Nmem, l0, csz;
        if (ch < 4) { mem = enc;  Nmem = Ll; csz = 25; l0 = ch * 25; }
        else        { mem = conv; Nmem = Rr; csz = 31; l0 = (ch - 4) * 31; }
        int l1 = min(Nmem, l0 + csz);
        const float4* Wb4 = (const float4*)Wb;
        float4 w4[4];
        #pragma unroll
        for (int it = 0; it < 4; ++it) {
            int idx = lane + it*64;
            w4[it] = (idx < 250) ? Wb4[idx] : (float4){0.f,0.f,0.f,0.f};
        }
        float4 cx[4] = {{0,0,0,0},{0,0,0,0},{0,0,0,0},{0,0,0,0}};
        float ssum = 0.f;
        const float* base = mem + (size_t)b * Nmem * 1000;
        for (int l = l0 + wv; l < l1; l += 4) {
            const float4* r4 = (const float4*)(base + (size_t)l * 1000);
            float4 v[4];
            float s = 0.f;
            #pragma unroll
            for (int it = 0; it < 4; ++it) {
                int idx = lane + it*64;
                v[it] = (idx < 250) ? r4[idx] : (float4){0.f,0.f,0.f,0.f};
                s += v[it].x*w4[it].x + v[it].y*w4[it].y + v[it].z*w4[it].z + v[it].w*w4[it].w;
            }
            #pragma unroll
            for (int off = 32; off > 0; off >>= 1) s += __shfl_xor(s, off);
            float wgt = __expf(s - 8.f);
            ssum += wgt;
            #pragma unroll
            for (int it = 0; it < 4; ++it) {
                cx[it].x += wgt*v[it].x; cx[it].y += wgt*v[it].y;
                cx[it].z += wgt*v[it].z; cx[it].w += wgt*v[it].w;
            }
        }
        #pragma unroll
        for (int it = 0; it < 4; ++it) sbuf4[wv*256 + lane + it*64] = cx[it];
        if (lane == 0) sredA[wv] = ssum;
        __syncthreads();
        if (tid < 250) {
            float4 a0 = sbuf4[tid], a1 = sbuf4[256+tid], a2 = sbuf4[512+tid], a3 = sbuf4[768+tid];
            float4 acc = {a0.x+a1.x+a2.x+a3.x, a0.y+a1.y+a2.y+a3.y,
                          a0.z+a1.z+a2.z+a3.z, a0.w+a1.w+a2.w+a3.w};
            *(float4*)(part_ctx + (size_t)id * 1000 + tid*4) = acc;
        }
        if (tid == 0) part_ss[id] = sredA[0] + sredA[1] + sredA[2] + sredA[3];
        return;
    }
    // ---------------- weight packing ----------------
    float (*tile)[33] = (float(*)[33])sbuf4;
    int id2 = id - 3072;
    int tx = tid & 31, ty = tid >> 5;
    if (id2 < 3072) {                        // W_hh -> Wp (packed gates, transposed)
        int k0 = (id2 & 31) * 32, n0v = (id2 >> 5) * 32;
        for (int i = ty; i < 32; i += 8) {
            int k = k0 + i, np = n0v + tx;
            int part, j; unpack_col(np, part, j);
            tile[i][tx] = (k < Hh && j < Hh) ? W_hh[(size_t)k*3000 + part*1000 + j] : 0.f;
        }
        __syncthreads();
        for (int i = ty; i < 32; i += 8) {
            int np = n0v + i, k = k0 + tx;
            Wp[(size_t)np*KP_G + k] = f2bf(tile[tx][i]);
        }
    } else if (id2 < 3456) {                 // W_ih -> Wihpb
        int lid = id2 - 3072;
        int k0 = (lid & 3) * 32, n0v = (lid >> 2) * 32;
        for (int i = ty; i < 32; i += 8) {
            int k = k0 + i, np = n0v + tx;
            int part, j; unpack_col(np, part, j);
            tile[i][tx] = (k < Ee && j < Hh) ? W_ih[(size_t)k*3000 + part*1000 + j] : 0.f;
        }
        __syncthreads();
        for (int i = ty; i < 32; i += 8) {
            int np = n0v + i, k = k0 + tx;
            Wihpb[(size_t)np*KP_E + k] = f2bf(tile[tx][i]);
        }
    } else if (id2 < 4224) {                 // W_pred / W_fuse transposes
        int lid = id2 - 3456;
        int z = lid >> 8; int rem = lid & 255;
        int k0 = (rem & 31) * 32, n0v = (rem >> 5) * 32;
        const float* src; int srcLd, nValid, row0; unsigned short* dst; int nRows;
        if (z == 0)      { src = W_pred; srcLd = 247; nValid = 247; row0 = 0;    dst = Wheads;                    nRows = 256; }
        else if (z == 1) { if (n0v >= 128) return;
                           src = W_fuse; srcLd = 100; nValid = 100; row0 = 0;    dst = Wheads + (size_t)256*KP_G; nRows = 128; }
        else             { if (n0v >= 128) return;
                           src = W_fuse; srcLd = 100; nValid = 100; row0 = 1000; dst = Wfb;                       nRows = 128; }
        for (int i = ty; i < 32; i += 8) {
            int k = k0 + i, n = n0v + tx;
            tile[i][tx] = (k < Hh && n < nValid) ? src[(size_t)(row0 + k)*srcLd + n] : 0.f;
        }
        __syncthreads();
        for (int i = ty; i < 32; i += 8) {
            int n = n0v + i, k = k0 + tx;
            if (n < nRows && !(z == 0 && n == 247))   // row 247 owned by misc seg (eos)
                dst[(size_t)n*KP_G + k] = f2bf(tile[tx][i]);
        }
    } else {                                // h0 cvt + bias packing
        int bid2 = id2 - 4224;
        if (bid2 < 1024) {
            int i = bid2*256 + tid;
            int bb = i >> 10, j = i & 1023;
            float v = (j < Hh) ? h0[(size_t)bb*Hh + j] : 0.f;
            h0b[i] = f2bf(v);
            h0f[i] = v;
        } else {
            int i = (bid2 - 1024)*256 + tid;
            if (i < NCP) {
                int part, j; unpack_col(i, part, j);
                bhhp[i] = (j < Hh) ? b_hh[part*1000 + j] : 0.f;
                bihp[i] = (j < Hh) ? b_ih[part*1000 + j] : 0.f;
            }
            if (i < 384) bias384[i] = (i < 247) ? b_pred[i] : (i == 247 ? b_eos[0] : 0.f);
            if (i < 128) bfuse128[i] = (i < 100) ? b_fuse[i] : 0.f;
            if (i < KP_G) Wheads[(size_t)247*KP_G + i] = f2bf(i < Hh ? W_eos[i] : 0.f);
        }
    }
}

// ========== fused: combine partials -> contexts -> xc/xrc -> x_allb =========
// one block per batch b; partials are plain sums (uniform shift) -> just divide
__launch_bounds__(256)
__global__ void fused_ctx(const float* __restrict__ pss, const float* __restrict__ pc,
                          const float* __restrict__ W_comb, const float* __restrict__ b_comb,
                          const float* __restrict__ emb, unsigned short* __restrict__ x_allb) {
    __shared__ float sc[1000];
    __shared__ float srd[1000];
    __shared__ float sWt[10000];   // W_comb top 100x100
    __shared__ float semb[1500];   // emb[b] 15x100
    __shared__ float sxc[100], sxrc[100];
    int b = blockIdx.x, tid = threadIdx.x;
    float te = 0.f, tc = 0.f;
    #pragma unroll
    for (int c = 0; c < 4; ++c) te += pss[b*12 + c];
    #pragma unroll
    for (int c = 0; c < 8; ++c) tc += pss[b*12 + 4 + c];
    float ive = 1.f/te, ivc = 1.f/tc;
    if (tid < 250) {
        float4 aE = {0,0,0,0}, aC = {0,0,0,0};
        #pragma unroll
        for (int c = 0; c < 4; ++c) {
            float4 v = *(const float4*)(pc + (size_t)(b*12 + c)*1000 + tid*4);
            aE.x += v.x; aE.y += v.y; aE.z += v.z; aE.w += v.w;
        }
        #pragma unroll
        for (int c = 0; c < 8; ++c) {
            float4 v = *(const float4*)(pc + (size_t)(b*12 + 4 + c)*1000 + tid*4);
            aC.x += v.x; aC.y += v.y; aC.z += v.z; aC.w += v.w;
        }
        aE.x *= ive; aE.y *= ive; aE.z *= ive; aE.w *= ive;
        aC.x *= ivc; aC.y *= ivc; aC.z *= ivc; aC.w *= ivc;
        *(float4*)&sc[tid*4]  = aE;
        *(float4*)&srd[tid*4] = aC;
    }
    for (int i = tid; i < 10000; i += 256) sWt[i] = W_comb[i];           // rows 0..99
    for (int i = tid; i < 1500;  i += 256) semb[i] = emb[(size_t)b*1500 + i];
    __syncthreads();
    if (tid < 100) {
        float a0 = 0.f, a1 = 0.f;
        #pragma unroll 4
        for (int k = 0; k < 1000; ++k) {
            float w = W_comb[(size_t)(100 + k)*100 + tid];
            a0 += sc[k]*w; a1 += srd[k]*w;
        }
        sxc[tid]  = a0 + b_comb[tid];
        sxrc[tid] = a1 + b_comb[tid];
    }
    __syncthreads();
    #pragma unroll
    for (int pass = 0; pass < 8; ++pass) {
        int t = pass*2 + (tid >> 7);
        int col = tid & 127;
        if (t < Tt) {
            float v = 0.f;
            if (col < 100) {
                float a = 0.f;
                #pragma unroll 4
                for (int k = 0; k < 100; ++k) a += semb[t*100 + k] * sWt[k*100 + col];
                v = a + ((t % 3 == 0) ? sxrc[col] : sxc[col]);
            }
            x_allb[((size_t)t*Bb + b)*KP_E + col] = f2bf(v);
        }
    }
}

// ================= bf16 MFMA GEMM body (shared by heads/encf) ================
// AMODE 1: A fp32 [M][1000], selu. AMODE 3: A bf16 [M][KTOT], selu iff n0>=seluStart.
template<int AMODE, int KTOT>
__device__ __forceinline__
void gemm_body(int m0, int n0, const void* __restrict__ Aptr,
               const unsigned short* __restrict__ Bt, const float* __restrict__ bias,
               float* __restrict__ C, int ldc, int seluStart,
               unsigned short* As, unsigned short* Bs) {
    constexpr int BK = 64, KP = 72;
    int tid = threadIdx.x;
    int lane = tid & 63, wid = tid >> 6;
    int wm = wid >> 1, wn = wid & 1;
    bool doSelu = (AMODE == 1) || (AMODE == 3 && n0 >= seluStart);
    f32x4 acc[2][4];
    #pragma unroll
    for (int i = 0; i < 2; i++)
        #pragma unroll
        for (int j = 0; j < 4; j++) acc[i][j] = (f32x4){0.f, 0.f, 0.f, 0.f};

    for (int k0 = 0; k0 < KTOT; k0 += BK) {
        #pragma unroll
        for (int e = 0; e < 2; ++e) {
            int idx = tid + e*256;
            int row = idx >> 3, kc = idx & 7;
            int k = k0 + kc*8;
            int rg = m0 + row;
            bf16x8 v;
            if (AMODE == 1) {
                if (k < Hh) {
                    const float4* p = (const float4*)((const float*)Aptr + (size_t)rg*Hh + k);
                    float4 x = p[0], y = p[1];
                    v[0]=(short)f2bf(selu_f(x.x)); v[1]=(short)f2bf(selu_f(x.y));
                    v[2]=(short)f2bf(selu_f(x.z)); v[3]=(short)f2bf(selu_f(x.w));
                    v[4]=(short)f2bf(selu_f(y.x)); v[5]=(short)f2bf(selu_f(y.y));
                    v[6]=(short)f2bf(selu_f(y.z)); v[7]=(short)f2bf(selu_f(y.w));
                } else {
                    #pragma unroll
                    for (int j = 0; j < 8; j++) v[j] = 0;
                }
            } else {
                v = *(const bf16x8*)((const unsigned short*)Aptr + (size_t)rg*KTOT + k);
                if (doSelu) {
                    #pragma unroll
                    for (int j = 0; j < 8; j++)
                        v[j] = (short)f2bf(selu_f(bf2f((unsigned short)v[j])));
                }
            }
            *(bf16x8*)(&As[row*KP + kc*8]) = v;
        }
        #pragma unroll
        for (int e = 0; e < 4; ++e) {
            int idx = tid + e*256;
            int row = idx >> 3, kc = idx & 7;
            bf16x8 v = *(const bf16x8*)(Bt + (size_t)(n0 + row)*KTOT + k0 + kc*8);
            *(bf16x8*)(&Bs[row*KP + kc*8]) = v;
        }
        __syncthreads();
        #pragma unroll
        for (int kk = 0; kk < 2; ++kk) {
            bf16x8 af[2], bfr[4];
            #pragma unroll
            for (int mi = 0; mi < 2; mi++)
                af[mi] = *(const bf16x8*)(&As[(wm*32 + mi*16 + (lane & 15))*KP + kk*32 + (lane >> 4)*8]);
            #pragma unroll
            for (int ni = 0; ni < 4; ni++)
                bfr[ni] = *(const bf16x8*)(&Bs[(wn*64 + ni*16 + (lane & 15))*KP + kk*32 + (lane >> 4)*8]);
            #pragma unroll
            for (int mi = 0; mi < 2; mi++)
                #pragma unroll
                for (int ni = 0; ni < 4; ni++)
                    acc[mi][ni] = __builtin_amdgcn_mfma_f32_16x16x32_bf16(af[mi], bfr[ni], acc[mi][ni], 0, 0, 0);
        }
        __syncthreads();
    }
    int cr = (lane >> 4) * 4, cc = lane & 15;
    #pragma unroll
    for (int mi = 0; mi < 2; mi++) {
        #pragma unroll
        for (int ni = 0; ni < 4; ni++) {
            int col = n0 + wn*64 + ni*16 + cc;
            float bv = bias ? bias[col] : 0.f;
            #pragma unroll
            for (int r = 0; r < 4; r++) {
                int row = m0 + wm*32 + mi*16 + cr + r;
                C[(size_t)row*ldc + col] = acc[mi][ni][r] + bv;
            }
        }
    }
}

// merged launch: blocks [0,180) = heads GEMM over all (t,b); [180,580) = encf GEMM
__launch_bounds__(256)
__global__ void heads_encf(const unsigned short* __restrict__ hb_all,
                           const unsigned short* __restrict__ Wheads,
                           const float* __restrict__ bias384, float* __restrict__ pf,
                           const float* __restrict__ enc, const unsigned short* __restrict__ Wfb,
                           const float* __restrict__ bfuse128, float* __restrict__ encf) {
    __shared__ unsigned short As[64 * 72];
    __shared__ unsigned short Bs[128 * 72];
    int id = blockIdx.x;
    if (id < 180) {
        int n0 = (id % 3) * 128, m0 = (id / 3) * 64;
        gemm_body<3, KP_G>(m0, n0, hb_all, Wheads, bias384, pf, 384, 256, As, Bs);
    } else {
        int m0 = (id - 180) * 64;
        gemm_body<1, KP_G>(m0, 0, enc, Wfb, bfuse128, encf, 128, 0, As, Bs);
    }
}

// ====== fused GRU step: LDS-free, barrier-free, fully-unrolled ==============
// grid (32, 8): n-tiles of 96 (2 gate-groups), m-tiles of 32. 4 waves (2m x 2n).
// MFMA fragments loaded DIRECTLY from global (row-major layouts match fragment
// rows exactly); Wp slices are L2-resident. 144 independent 16B loads/lane ->
// deep compiler software pipelining.
__launch_bounds__(256)
__global__ void gru_step(const unsigned short* __restrict__ hbA,
                         const unsigned short* __restrict__ xab,
                         const unsigned short* __restrict__ Wp,
                         const unsigned short* __restrict__ Wihpb,
                         const float* __restrict__ bhhp, const float* __restrict__ bihp,
                         const float* __restrict__ hprevf, float* __restrict__ hnextf,
                         unsigned short* __restrict__ hb_out) {
    int tid = threadIdx.x, lane = tid & 63, wid = tid >> 6;
    int wm = wid >> 1, wn = wid & 1;
    int n0 = blockIdx.x * 96, m0 = blockIdx.y * 32;
    int fr = lane & 15, koff = (lane >> 4) * 8;

    const unsigned short* ha = hbA + (size_t)(m0 + wm*16 + fr)*KP_G + koff;
    const unsigned short* xa = xab + (size_t)(m0 + wm*16 + fr)*KP_E + koff;
    const unsigned short* wr = Wp + (size_t)(n0 + wn*48 + fr)*KP_G + koff;
    const unsigned short* wz = wr + (size_t)16*KP_G;
    const unsigned short* wnn = wr + (size_t)32*KP_G;
    const unsigned short* xr = Wihpb + (size_t)(n0 + wn*48 + fr)*KP_E + koff;
    const unsigned short* xz = xr + (size_t)16*KP_E;
    const unsigned short* xn = xr + (size_t)32*KP_E;

    f32x4 acc0 = {0,0,0,0}, acc1 = {0,0,0,0}, acc2 = {0,0,0,0}, acc3 = {0,0,0,0};
    #pragma unroll
    for (int kb = 0; kb < 32; ++kb) {          // h part: K=1024
        int k = kb*32;
        bf16x8 af = *(const bf16x8*)(ha + k);
        acc0 = __builtin_amdgcn_mfma_f32_16x16x32_bf16(af, *(const bf16x8*)(wr + k), acc0, 0, 0, 0);
        acc1 = __builtin_amdgcn_mfma_f32_16x16x32_bf16(af, *(const bf16x8*)(wz + k), acc1, 0, 0, 0);
        acc2 = __builtin_amdgcn_mfma_f32_16x16x32_bf16(af, *(const bf16x8*)(wnn + k), acc2, 0, 0, 0);
    }
    #pragma unroll
    for (int kb = 0; kb < 4; ++kb) {           // x part: K=128 (gi_n separate in acc3)
        int k = kb*32;
        bf16x8 af = *(const bf16x8*)(xa + k);
        acc0 = __builtin_amdgcn_mfma_f32_16x16x32_bf16(af, *(const bf16x8*)(xr + k), acc0, 0, 0, 0);
        acc1 = __builtin_amdgcn_mfma_f32_16x16x32_bf16(af, *(const bf16x8*)(xz + k), acc1, 0, 0, 0);
        acc3 = __builtin_amdgcn_mfma_f32_16x16x32_bf16(af, *(const bf16x8*)(xn + k), acc3, 0, 0, 0);
    }

    // epilogue: lane holds gates for j = g*16 + c, rows m0 + wm*16 + (lane>>4)*4 + r
    int c = lane & 15, r0q = (lane >> 4) * 4;
    int g = n0 / 48 + wn;
    int j = g * 16 + c;
    float br = bhhp[g*48 + c]      + bihp[g*48 + c];
    float bz = bhhp[g*48 + 16 + c] + bihp[g*48 + 16 + c];
    float bn_h = bhhp[g*48 + 32 + c], bn_i = bihp[g*48 + 32 + c];
    #pragma unroll
    for (int r = 0; r < 4; r++) {
        int row = m0 + wm*16 + r0q + r;
        float rr = 1.f/(1.f + __expf(-(acc0[r] + br)));
        float zz = 1.f/(1.f + __expf(-(acc1[r] + bz)));
        float nn = tanhf(acc3[r] + bn_i + rr * (acc2[r] + bn_h));
        float hp = hprevf[(size_t)row*KP_G + j];
        float h = (1.f - zz)*nn + zz*hp;
        hnextf[(size_t)row*KP_G + j] = h;
        hb_out[(size_t)row*KP_G + j] = f2bf(h);
    }
}

// ================= per-(t,b) outputs, b-major grid for encf locality ========
__global__ void output_kernel(const float* __restrict__ pf, const float* __restrict__ encf,
                              const float* __restrict__ W_copy, const float* __restrict__ b_copy,
                              float* __restrict__ out) {
    __shared__ float sf[100];
    __shared__ float swc[100];
    __shared__ float scp[104];
    __shared__ float smx[4], ssx[4], smy[4], ssy[4];
    int bid = blockIdx.x;
    int b = bid / Tt, t = bid % Tt;     // consecutive blocks share b -> encf L2 hits
    int row = t*256 + b;
    int tid = threadIdx.x, lane = tid & 63, wv = tid >> 6;
    const float* pr = pf + (size_t)row * 384;
    if (tid < 100) { sf[tid] = pr[256 + tid]; swc[tid] = W_copy[tid]; }
    float x = (tid < 248) ? pr[tid] : -1e30f;
    if (tid == 247) scp[100] = x;       // eos into copy slot
    __syncthreads();                    // A: sf/swc ready
    const float* efb = encf + (size_t)b*Ll*128;
    for (int l = wv; l < Ll; l += 4) {
        const float* ef = efb + (size_t)l*128;
        float pp = selu_f(sf[lane] + ef[lane]) * swc[lane];
        if (lane < 36) pp += selu_f(sf[lane+64] + ef[lane+64]) * swc[lane+64];
        #pragma unroll
        for (int off = 32; off > 0; off >>= 1) pp += __shfl_down(pp, off);
        if (lane == 0) scp[l] = pp + b_copy[0];
    }
    float mx = x;
    #pragma unroll
    for (int off = 32; off > 0; off >>= 1) mx = fmaxf(mx, __shfl_xor(mx, off));
    if (lane == 0) smx[wv] = mx;
    __syncthreads();                    // B: scp + smx ready
    float m_x = fmaxf(fmaxf(smx[0], smx[1]), fmaxf(smx[2], smx[3]));
    float ex = (tid < 248) ? __expf(x - m_x) : 0.f;
    float sx = ex;
    #pragma unroll
    for (int off = 32; off > 0; off >>= 1) sx += __shfl_xor(sx, off);
    if (lane == 0) ssx[wv] = sx;
    float y = (tid < 101) ? scp[tid] : -1e30f;
    float my = y;
    #pragma unroll
    for (int off = 32; off > 0; off >>= 1) my = fmaxf(my, __shfl_xor(my, off));
    if (lane == 0) smy[wv] = my;
    __syncthreads();                    // C
    float* ob = out + (size_t)row*OUTW;
    float lse_x = m_x + __logf(ssx[0] + ssx[1] + ssx[2] + ssx[3]);
    if (tid < 248) ob[tid] = x - lse_x;
    float m_y = fmaxf(fmaxf(smy[0], smy[1]), fmaxf(smy[2], smy[3]));
    float ey = (tid < 101) ? __expf(y - m_y) : 0.f;
    float sy = ey;
    #pragma unroll
    for (int off = 32; off > 0; off >>= 1) sy += __shfl_xor(sy, off);
    if (lane == 0) ssy[wv] = sy;
    __syncthreads();                    // D
    float lse_y = m_y + __logf(ssy[0] + ssy[1] + ssy[2] + ssy[3]);
    if (tid < 101) ob[248 + tid] = y - lse_y;
}

// ============================================================================
extern "C" void kernel_launch(void* const* d_in, const int* in_sizes, int n_in,
                              void* d_out, int out_size, void* d_ws, size_t ws_size,
                              hipStream_t stream) {
    const float* emb    = (const float*)d_in[0];
    const float* enc    = (const float*)d_in[1];
    const float* conv   = (const float*)d_in[2];
    const float* h0     = (const float*)d_in[3];
    const float* W_attn = (const float*)d_in[4];
    const float* W_comb = (const float*)d_in[6];
    const float* b_comb = (const float*)d_in[7];
    const float* W_ih   = (const float*)d_in[8];
    const float* W_hh   = (const float*)d_in[9];
    const float* b_ih   = (const float*)d_in[10];
    const float* b_hh   = (const float*)d_in[11];
    const float* W_eos  = (const float*)d_in[12];
    const float* b_eos  = (const float*)d_in[13];
    const float* W_pred = (const float*)d_in[14];
    const float* b_pred = (const float*)d_in[15];
    const float* W_fuse = (const float*)d_in[16];
    const float* b_fuse = (const float*)d_in[17];
    const float* W_copy = (const float*)d_in[18];
    const float* b_copy = (const float*)d_in[19];
    float* out = (float*)d_out;

    char* p = (char*)d_ws;
    auto alloc = [&](size_t bytes) -> void* {
        void* r = (void*)p; p += (bytes + 255) & ~(size_t)255; return r;
    };
    float* pss    = (float*)alloc((size_t)Bb*12*4);
    float* pc     = (float*)alloc((size_t)Bb*12*1000*4);
    unsigned short* x_allb = (unsigned short*)alloc((size_t)Tt*Bb*KP_E*2);
    float* encf   = (float*)alloc((size_t)Bb*Ll*128*4);
    unsigned short* Wp     = (unsigned short*)alloc((size_t)NCP*KP_G*2);
    unsigned short* Wihpb  = (unsigned short*)alloc((size_t)NCP*KP_E*2);
    unsigned short* Wheads = (unsigned short*)alloc((size_t)384*KP_G*2);
    unsigned short* Wfb    = (unsigned short*)alloc((size_t)128*KP_G*2);
    float* bhhp     = (float*)alloc(NCP*4);
    float* bihp     = (float*)alloc(NCP*4);
    float* bias384  = (float*)alloc(384*4);
    float* bfuse128 = (float*)alloc(128*4);
    float* h_f[2];
    h_f[0] = (float*)alloc((size_t)Bb*KP_G*4);
    h_f[1] = (float*)alloc((size_t)Bb*KP_G*4);
    float* h0f = (float*)alloc((size_t)Bb*KP_G*4);
    unsigned short* h0b    = (unsigned short*)alloc((size_t)Bb*KP_G*2);
    unsigned short* hb_all = (unsigned short*)alloc((size_t)Tt*Bb*KP_G*2);
    float* pf = (float*)alloc((size_t)Tt*Bb*384*4);

    // ---- attention + ALL packing in ONE dispatch (independent work overlaps) ----
    attn_pack<<<3072 + 5260, 256, 0, stream>>>(
        enc, conv, W_attn + Hh, pss, pc,
        W_hh, W_ih, W_pred, W_fuse, h0, b_hh, b_ih, b_pred, b_eos, W_eos, b_fuse,
        Wp, Wihpb, Wheads, Wfb, h0b, h0f, bhhp, bihp, bias384, bfuse128);
    fused_ctx<<<Bb, 256, 0, stream>>>(pss, pc, W_comb, b_comb, emb, x_allb);

    // ---- serial GRU: LDS-free barrier-free kernel per step ----
    const unsigned short* hbprev = h0b;
    const float* hprev = h0f;
    for (int t = 0; t < Tt; ++t) {
        float* hnext = h_f[t & 1];
        unsigned short* hbnext = hb_all + (size_t)t*Bb*KP_G;
        gru_step<<<dim3(32, 8), 256, 0, stream>>>(hbprev, x_allb + (size_t)t*Bb*KP_E,
                                                  Wp, Wihpb, bhhp, bihp,
                                                  hprev, hnext, hbnext);
        hbprev = hbnext; hprev = hnext;
    }

    // ---- heads GEMM (t,b batched) + encf GEMM in ONE launch (580 blocks) ----
    heads_encf<<<580, 256, 0, stream>>>(hb_all, Wheads, bias384, pf, enc, Wfb, bfuse128, encf);
    output_kernel<<<Tt*Bb, 256, 0, stream>>>(pf, encf, W_copy, b_copy, out);
}

// Round 11
// 412.590 us; speedup vs baseline: 1.3724x; 1.3724x over previous
//
#include <hip/hip_runtime.h>
#include <hip/hip_bf16.h>
#include <math.h>

#define SELU_ALPHA 1.6732632423543772f
#define SELU_SCALE 1.0507009873554805f

typedef __attribute__((ext_vector_type(8))) short bf16x8;
typedef __attribute__((ext_vector_type(4))) float f32x4;

__device__ __forceinline__ float selu_f(float x) {
    return x > 0.f ? SELU_SCALE * x : SELU_SCALE * SELU_ALPHA * (__expf(x) - 1.f);
}
__device__ __forceinline__ unsigned short f2bf(float f) {
    __hip_bfloat16 h = __float2bfloat16(f);
    return *(unsigned short*)&h;
}
__device__ __forceinline__ float bf2f(unsigned short u) {
    unsigned int x = ((unsigned int)u) << 16;
    float f; __builtin_memcpy(&f, &x, 4); return f;
}

constexpr int Bb = 256, Ll = 100, Hh = 1000, Ee = 100, Rr = 247, Tt = 15;
constexpr int KP_G = 1024;             // padded K for H-sized bf16 GEMMs
constexpr int KP_E = 128;              // padded K for E-sized x rows
constexpr int NCP = 3072;              // packed gate cols: 64 groups x 48 (r16|z16|n16)
constexpr int OUTW = Rr + 1 + Ll + 1;  // 349

// map packed col n' -> (part, j).  g=n'/48, rem=n'%48, part=rem/16, c=rem%16, j=g*16+c
__device__ __forceinline__ void unpack_col(int np, int& part, int& j) {
    int g = np / 48, rem = np % 48;
    part = rem >> 4;
    j = g * 16 + (rem & 15);
}

// ======== merged: attention (blocks 0..3071) + ALL weight packing ===========
// attn: id = b*12 + ch; ch 0..3 enc (chunk 25), 4..11 conv (chunk 31).
// Barrier-free per-wave rows; softmax via fixed shift exp(s-8) (scores |s|<~8).
__launch_bounds__(256)
__global__ void attn_pack(const float* __restrict__ enc, const float* __restrict__ conv,
                          const float* __restrict__ Wb,
                          float* __restrict__ part_ss, float* __restrict__ part_ctx,
                          const float* __restrict__ W_hh, const float* __restrict__ W_ih,
                          const float* __restrict__ W_pred, const float* __restrict__ W_fuse,
                          const float* __restrict__ h0, const float* __restrict__ b_hh,
                          const float* __restrict__ b_ih, const float* __restrict__ b_pred,
                          const float* __restrict__ b_eos, const float* __restrict__ W_eos,
                          const float* __restrict__ b_fuse,
                          unsigned short* __restrict__ Wp, unsigned short* __restrict__ Wihpb,
                          unsigned short* __restrict__ Wheads, unsigned short* __restrict__ Wfb,
                          unsigned short* __restrict__ h0b, float* __restrict__ h0f,
                          float* __restrict__ bhhp, float* __restrict__ bihp,
                          float* __restrict__ bias384, float* __restrict__ bfuse128) {
    __shared__ float4 sbuf4[4 * 256];     // attn: per-wave ctx partials (16 KB)
    __shared__ float sredA[4];
    int id = blockIdx.x, tid = threadIdx.x;
    int lane = tid & 63, wv = tid >> 6;
    if (id < 3072) {
        // ---------------- attention ----------------
        int b = id / 12, ch = id % 12;
        const float* mem; int Nmem, l0, csz;
        if (ch < 4) { mem = enc;  Nmem = Ll; csz = 25; l0 = ch * 25; }
        else        { mem = conv; Nmem = Rr; csz = 31; l0 = (ch - 4) * 31; }
        int l1 = min(Nmem, l0 + csz);
        const float4* Wb4 = (const float4*)Wb;
        float4 w4[4];
        #pragma unroll
        for (int it = 0; it < 4; ++it) {
            int idx = lane + it*64;
            w4[it] = (idx < 250) ? Wb4[idx] : (float4){0.f,0.f,0.f,0.f};
        }
        float4 cx[4] = {{0,0,0,0},{0,0,0,0},{0,0,0,0},{0,0,0,0}};
        float ssum = 0.f;
        const float* base = mem + (size_t)b * Nmem * 1000;
        for (int l = l0 + wv; l < l1; l += 4) {
            const float4* r4 = (const float4*)(base + (size_t)l * 1000);
            float4 v[4];
            float s = 0.f;
            #pragma unroll
            for (int it = 0; it < 4; ++it) {
                int idx = lane + it*64;
                v[it] = (idx < 250) ? r4[idx] : (float4){0.f,0.f,0.f,0.f};
                s += v[it].x*w4[it].x + v[it].y*w4[it].y + v[it].z*w4[it].z + v[it].w*w4[it].w;
            }
            #pragma unroll
            for (int off = 32; off > 0; off >>= 1) s += __shfl_xor(s, off);
            float wgt = __expf(s - 8.f);
            ssum += wgt;
            #pragma unroll
            for (int it = 0; it < 4; ++it) {
                cx[it].x += wgt*v[it].x; cx[it].y += wgt*v[it].y;
                cx[it].z += wgt*v[it].z; cx[it].w += wgt*v[it].w;
            }
        }
        #pragma unroll
        for (int it = 0; it < 4; ++it) sbuf4[wv*256 + lane + it*64] = cx[it];
        if (lane == 0) sredA[wv] = ssum;
        __syncthreads();
        if (tid < 250) {
            float4 a0 = sbuf4[tid], a1 = sbuf4[256+tid], a2 = sbuf4[512+tid], a3 = sbuf4[768+tid];
            float4 acc = {a0.x+a1.x+a2.x+a3.x, a0.y+a1.y+a2.y+a3.y,
                          a0.z+a1.z+a2.z+a3.z, a0.w+a1.w+a2.w+a3.w};
            *(float4*)(part_ctx + (size_t)id * 1000 + tid*4) = acc;
        }
        if (tid == 0) part_ss[id] = sredA[0] + sredA[1] + sredA[2] + sredA[3];
        return;
    }
    // ---------------- weight packing ----------------
    float (*tile)[33] = (float(*)[33])sbuf4;
    int id2 = id - 3072;
    int tx = tid & 31, ty = tid >> 5;
    if (id2 < 3072) {                        // W_hh -> Wp (packed gates, transposed)
        int k0 = (id2 & 31) * 32, n0v = (id2 >> 5) * 32;
        for (int i = ty; i < 32; i += 8) {
            int k = k0 + i, np = n0v + tx;
            int part, j; unpack_col(np, part, j);
            tile[i][tx] = (k < Hh && j < Hh) ? W_hh[(size_t)k*3000 + part*1000 + j] : 0.f;
        }
        __syncthreads();
        for (int i = ty; i < 32; i += 8) {
            int np = n0v + i, k = k0 + tx;
            Wp[(size_t)np*KP_G + k] = f2bf(tile[tx][i]);
        }
    } else if (id2 < 3456) {                 // W_ih -> Wihpb
        int lid = id2 - 3072;
        int k0 = (lid & 3) * 32, n0v = (lid >> 2) * 32;
        for (int i = ty; i < 32; i += 8) {
            int k = k0 + i, np = n0v + tx;
            int part, j; unpack_col(np, part, j);
            tile[i][tx] = (k < Ee && j < Hh) ? W_ih[(size_t)k*3000 + part*1000 + j] : 0.f;
        }
        __syncthreads();
        for (int i = ty; i < 32; i += 8) {
            int np = n0v + i, k = k0 + tx;
            Wihpb[(size_t)np*KP_E + k] = f2bf(tile[tx][i]);
        }
    } else if (id2 < 4224) {                 // W_pred / W_fuse transposes
        int lid = id2 - 3456;
        int z = lid >> 8; int rem = lid & 255;
        int k0 = (rem & 31) * 32, n0v = (rem >> 5) * 32;
        const float* src; int srcLd, nValid, row0; unsigned short* dst; int nRows;
        if (z == 0)      { src = W_pred; srcLd = 247; nValid = 247; row0 = 0;    dst = Wheads;                    nRows = 256; }
        else if (z == 1) { if (n0v >= 128) return;
                           src = W_fuse; srcLd = 100; nValid = 100; row0 = 0;    dst = Wheads + (size_t)256*KP_G; nRows = 128; }
        else             { if (n0v >= 128) return;
                           src = W_fuse; srcLd = 100; nValid = 100; row0 = 1000; dst = Wfb;                       nRows = 128; }
        for (int i = ty; i < 32; i += 8) {
            int k = k0 + i, n = n0v + tx;
            tile[i][tx] = (k < Hh && n < nValid) ? src[(size_t)(row0 + k)*srcLd + n] : 0.f;
        }
        __syncthreads();
        for (int i = ty; i < 32; i += 8) {
            int n = n0v + i, k = k0 + tx;
            if (n < nRows && !(z == 0 && n == 247))   // row 247 owned by misc seg (eos)
                dst[(size_t)n*KP_G + k] = f2bf(tile[tx][i]);
        }
    } else {                                // h0 cvt + bias packing
        int bid2 = id2 - 4224;
        if (bid2 < 1024) {
            int i = bid2*256 + tid;
            int bb = i >> 10, j = i & 1023;
            float v = (j < Hh) ? h0[(size_t)bb*Hh + j] : 0.f;
            h0b[i] = f2bf(v);
            h0f[i] = v;
        } else {
            int i = (bid2 - 1024)*256 + tid;
            if (i < NCP) {
                int part, j; unpack_col(i, part, j);
                bhhp[i] = (j < Hh) ? b_hh[part*1000 + j] : 0.f;
                bihp[i] = (j < Hh) ? b_ih[part*1000 + j] : 0.f;
            }
            if (i < 384) bias384[i] = (i < 247) ? b_pred[i] : (i == 247 ? b_eos[0] : 0.f);
            if (i < 128) bfuse128[i] = (i < 100) ? b_fuse[i] : 0.f;
            if (i < KP_G) Wheads[(size_t)247*KP_G + i] = f2bf(i < Hh ? W_eos[i] : 0.f);
        }
    }
}

// ========== fused: combine partials -> contexts -> xc/xrc -> x_allb =========
// one block per batch b; partials are plain sums (uniform shift) -> just divide
__launch_bounds__(256)
__global__ void fused_ctx(const float* __restrict__ pss, const float* __restrict__ pc,
                          const float* __restrict__ W_comb, const float* __restrict__ b_comb,
                          const float* __restrict__ emb, unsigned short* __restrict__ x_allb) {
    __shared__ float sc[1000];
    __shared__ float srd[1000];
    __shared__ float sWt[10000];   // W_comb top 100x100
    __shared__ float semb[1500];   // emb[b] 15x100
    __shared__ float sxc[100], sxrc[100];
    int b = blockIdx.x, tid = threadIdx.x;
    float te = 0.f, tc = 0.f;
    #pragma unroll
    for (int c = 0; c < 4; ++c) te += pss[b*12 + c];
    #pragma unroll
    for (int c = 0; c < 8; ++c) tc += pss[b*12 + 4 + c];
    float ive = 1.f/te, ivc = 1.f/tc;
    if (tid < 250) {
        float4 aE = {0,0,0,0}, aC = {0,0,0,0};
        #pragma unroll
        for (int c = 0; c < 4; ++c) {
            float4 v = *(const float4*)(pc + (size_t)(b*12 + c)*1000 + tid*4);
            aE.x += v.x; aE.y += v.y; aE.z += v.z; aE.w += v.w;
        }
        #pragma unroll
        for (int c = 0; c < 8; ++c) {
            float4 v = *(const float4*)(pc + (size_t)(b*12 + 4 + c)*1000 + tid*4);
            aC.x += v.x; aC.y += v.y; aC.z += v.z; aC.w += v.w;
        }
        aE.x *= ive; aE.y *= ive; aE.z *= ive; aE.w *= ive;
        aC.x *= ivc; aC.y *= ivc; aC.z *= ivc; aC.w *= ivc;
        *(float4*)&sc[tid*4]  = aE;
        *(float4*)&srd[tid*4] = aC;
    }
    for (int i = tid; i < 10000; i += 256) sWt[i] = W_comb[i];           // rows 0..99
    for (int i = tid; i < 1500;  i += 256) semb[i] = emb[(size_t)b*1500 + i];
    __syncthreads();
    if (tid < 100) {
        float a0 = 0.f, a1 = 0.f;
        #pragma unroll 4
        for (int k = 0; k < 1000; ++k) {
            float w = W_comb[(size_t)(100 + k)*100 + tid];
            a0 += sc[k]*w; a1 += srd[k]*w;
        }
        sxc[tid]  = a0 + b_comb[tid];
        sxrc[tid] = a1 + b_comb[tid];
    }
    __syncthreads();
    #pragma unroll
    for (int pass = 0; pass < 8; ++pass) {
        int t = pass*2 + (tid >> 7);
        int col = tid & 127;
        if (t < Tt) {
            float v = 0.f;
            if (col < 100) {
                float a = 0.f;
                #pragma unroll 4
                for (int k = 0; k < 100; ++k) a += semb[t*100 + k] * sWt[k*100 + col];
                v = a + ((t % 3 == 0) ? sxrc[col] : sxc[col]);
            }
            x_allb[((size_t)t*Bb + b)*KP_E + col] = f2bf(v);
        }
    }
}

// ================= bf16 MFMA GEMM body (shared by heads/encf) ================
// AMODE 1: A fp32 [M][1000], selu. AMODE 3: A bf16 [M][KTOT], selu iff n0>=seluStart.
template<int AMODE, int KTOT>
__device__ __forceinline__
void gemm_body(int m0, int n0, const void* __restrict__ Aptr,
               const unsigned short* __restrict__ Bt, const float* __restrict__ bias,
               float* __restrict__ C, int ldc, int seluStart,
               unsigned short* As, unsigned short* Bs) {
    constexpr int BK = 64, KP = 72;
    int tid = threadIdx.x;
    int lane = tid & 63, wid = tid >> 6;
    int wm = wid >> 1, wn = wid & 1;
    bool doSelu = (AMODE == 1) || (AMODE == 3 && n0 >= seluStart);
    f32x4 acc[2][4];
    #pragma unroll
    for (int i = 0; i < 2; i++)
        #pragma unroll
        for (int j = 0; j < 4; j++) acc[i][j] = (f32x4){0.f, 0.f, 0.f, 0.f};

    for (int k0 = 0; k0 < KTOT; k0 += BK) {
        #pragma unroll
        for (int e = 0; e < 2; ++e) {
            int idx = tid + e*256;
            int row = idx >> 3, kc = idx & 7;
            int k = k0 + kc*8;
            int rg = m0 + row;
            bf16x8 v;
            if (AMODE == 1) {
                if (k < Hh) {
                    const float4* p = (const float4*)((const float*)Aptr + (size_t)rg*Hh + k);
                    float4 x = p[0], y = p[1];
                    v[0]=(short)f2bf(selu_f(x.x)); v[1]=(short)f2bf(selu_f(x.y));
                    v[2]=(short)f2bf(selu_f(x.z)); v[3]=(short)f2bf(selu_f(x.w));
                    v[4]=(short)f2bf(selu_f(y.x)); v[5]=(short)f2bf(selu_f(y.y));
                    v[6]=(short)f2bf(selu_f(y.z)); v[7]=(short)f2bf(selu_f(y.w));
                } else {
                    #pragma unroll
                    for (int j = 0; j < 8; j++) v[j] = 0;
                }
            } else {
                v = *(const bf16x8*)((const unsigned short*)Aptr + (size_t)rg*KTOT + k);
                if (doSelu) {
                    #pragma unroll
                    for (int j = 0; j < 8; j++)
                        v[j] = (short)f2bf(selu_f(bf2f((unsigned short)v[j])));
                }
            }
            *(bf16x8*)(&As[row*KP + kc*8]) = v;
        }
        #pragma unroll
        for (int e = 0; e < 4; ++e) {
            int idx = tid + e*256;
            int row = idx >> 3, kc = idx & 7;
            bf16x8 v = *(const bf16x8*)(Bt + (size_t)(n0 + row)*KTOT + k0 + kc*8);
            *(bf16x8*)(&Bs[row*KP + kc*8]) = v;
        }
        __syncthreads();
        #pragma unroll
        for (int kk = 0; kk < 2; ++kk) {
            bf16x8 af[2], bfr[4];
            #pragma unroll
            for (int mi = 0; mi < 2; mi++)
                af[mi] = *(const bf16x8*)(&As[(wm*32 + mi*16 + (lane & 15))*KP + kk*32 + (lane >> 4)*8]);
            #pragma unroll
            for (int ni = 0; ni < 4; ni++)
                bfr[ni] = *(const bf16x8*)(&Bs[(wn*64 + ni*16 + (lane & 15))*KP + kk*32 + (lane >> 4)*8]);
            #pragma unroll
            for (int mi = 0; mi < 2; mi++)
                #pragma unroll
                for (int ni = 0; ni < 4; ni++)
                    acc[mi][ni] = __builtin_amdgcn_mfma_f32_16x16x32_bf16(af[mi], bfr[ni], acc[mi][ni], 0, 0, 0);
        }
        __syncthreads();
    }
    int cr = (lane >> 4) * 4, cc = lane & 15;
    #pragma unroll
    for (int mi = 0; mi < 2; mi++) {
        #pragma unroll
        for (int ni = 0; ni < 4; ni++) {
            int col = n0 + wn*64 + ni*16 + cc;
            float bv = bias ? bias[col] : 0.f;
            #pragma unroll
            for (int r = 0; r < 4; r++) {
                int row = m0 + wm*32 + mi*16 + cr + r;
                C[(size_t)row*ldc + col] = acc[mi][ni][r] + bv;
            }
        }
    }
}

// merged launch: blocks [0,180) = heads GEMM over all (t,b); [180,580) = encf GEMM
__launch_bounds__(256)
__global__ void heads_encf(const unsigned short* __restrict__ hb_all,
                           const unsigned short* __restrict__ Wheads,
                           const float* __restrict__ bias384, float* __restrict__ pf,
                           const float* __restrict__ enc, const unsigned short* __restrict__ Wfb,
                           const float* __restrict__ bfuse128, float* __restrict__ encf) {
    __shared__ unsigned short As[64 * 72];
    __shared__ unsigned short Bs[128 * 72];
    int id = blockIdx.x;
    if (id < 180) {
        int n0 = (id % 3) * 128, m0 = (id / 3) * 64;
        gemm_body<3, KP_G>(m0, n0, hb_all, Wheads, bias384, pf, 384, 256, As, Bs);
    } else {
        int m0 = (id - 180) * 64;
        gemm_body<1, KP_G>(m0, 0, enc, Wfb, bfuse128, encf, 128, 0, As, Bs);
    }
}

// ====== fused GRU step: (h@Whh + x@Wih) + gates; unrolled 2-deep pipeline ===
// grid (32, 8): n-tiles of 96 (2 gate-groups), m-tiles of 32. 4 waves (2m x 2n).
// 18 K-tiles of 64: tiles 0..15 from h/Wp, 16..17 from x/Wihpb — all branches
// compile-time via full unroll; loads issued 2 tiles ahead. [R9-proven]
__launch_bounds__(256)
__global__ void gru_step(const unsigned short* __restrict__ hbA,
                         const unsigned short* __restrict__ xab,
                         const unsigned short* __restrict__ Wp,
                         const unsigned short* __restrict__ Wihpb,
                         const float* __restrict__ bhhp, const float* __restrict__ bihp,
                         const float* __restrict__ hprevf, float* __restrict__ hnextf,
                         unsigned short* __restrict__ hb_out) {
    constexpr int KP = 72;
    __shared__ unsigned short As[2][32 * KP];
    __shared__ unsigned short Bs[2][96 * KP];
    int tid = threadIdx.x, lane = tid & 63, wid = tid >> 6;
    int wm = wid >> 1, wn = wid & 1;
    int n0 = blockIdx.x * 96, m0 = blockIdx.y * 32;
    int sr = tid >> 3, skc = tid & 7;

    const unsigned short* hA  = hbA + (size_t)(m0+sr)*KP_G + skc*8;
    const unsigned short* xA  = xab + (size_t)(m0+sr)*KP_E + skc*8;
    const unsigned short* wp0 = Wp  + (size_t)(n0+sr)*KP_G + skc*8;
    const unsigned short* wp1 = wp0 + (size_t)32*KP_G;
    const unsigned short* wp2 = wp0 + (size_t)64*KP_G;
    const unsigned short* wx0 = Wihpb + (size_t)(n0+sr)*KP_E + skc*8;
    const unsigned short* wx1 = wx0 + (size_t)32*KP_E;
    const unsigned short* wx2 = wx0 + (size_t)64*KP_E;

    auto loadT = [&](int t, bf16x8& ra, bf16x8& b0, bf16x8& b1, bf16x8& b2) {
        if (t < 16) {
            int k = t*64;
            ra = *(const bf16x8*)(hA  + k);
            b0 = *(const bf16x8*)(wp0 + k);
            b1 = *(const bf16x8*)(wp1 + k);
            b2 = *(const bf16x8*)(wp2 + k);
        } else {
            int k = (t-16)*64;
            ra = *(const bf16x8*)(xA  + k);
            b0 = *(const bf16x8*)(wx0 + k);
            b1 = *(const bf16x8*)(wx1 + k);
            b2 = *(const bf16x8*)(wx2 + k);
        }
    };
    int sA = sr*KP + skc*8;
    int sB0 = sA, sB1 = (sr+32)*KP + skc*8, sB2 = (sr+64)*KP + skc*8;

    f32x4 acc0 = {0,0,0,0}, acc1 = {0,0,0,0}, acc2 = {0,0,0,0}, acc3 = {0,0,0,0};

    bf16x8 rA[2], rB0[2], rB1[2], rB2[2];
    // prologue: tile 0 -> LDS[0]; tile 1 -> regs slot 1
    loadT(0, rA[0], rB0[0], rB1[0], rB2[0]);
    *(bf16x8*)&As[0][sA]  = rA[0];
    *(bf16x8*)&Bs[0][sB0] = rB0[0];
    *(bf16x8*)&Bs[0][sB1] = rB1[0];
    *(bf16x8*)&Bs[0][sB2] = rB2[0];
    loadT(1, rA[1], rB0[1], rB1[1], rB2[1]);
    __syncthreads();

    int aoff  = (wm*16 + (lane & 15))*KP + (lane >> 4)*8;
    int boff0 = (wn*48 + (lane & 15))*KP + (lane >> 4)*8;
    int boff1 = boff0 + 16*KP, boff2 = boff0 + 32*KP;

    #pragma unroll
    for (int t = 0; t < 18; ++t) {
        int cur = t & 1, nxt = cur ^ 1;
        if (t + 2 < 18) loadT(t+2, rA[cur], rB0[cur], rB1[cur], rB2[cur]);  // slot cur is free
        #pragma unroll
        for (int kk = 0; kk < 2; ++kk) {
            bf16x8 af = *(const bf16x8*)(&As[cur][aoff + kk*32]);
            acc0 = __builtin_amdgcn_mfma_f32_16x16x32_bf16(af, *(const bf16x8*)(&Bs[cur][boff0 + kk*32]), acc0, 0, 0, 0);
            acc1 = __builtin_amdgcn_mfma_f32_16x16x32_bf16(af, *(const bf16x8*)(&Bs[cur][boff1 + kk*32]), acc1, 0, 0, 0);
            bf16x8 b2v = *(const bf16x8*)(&Bs[cur][boff2 + kk*32]);
            if (t < 16) acc2 = __builtin_amdgcn_mfma_f32_16x16x32_bf16(af, b2v, acc2, 0, 0, 0);
            else        acc3 = __builtin_amdgcn_mfma_f32_16x16x32_bf16(af, b2v, acc3, 0, 0, 0);
        }
        if (t + 1 < 18) {
            *(bf16x8*)&As[nxt][sA]  = rA[nxt];
            *(bf16x8*)&Bs[nxt][sB0] = rB0[nxt];
            *(bf16x8*)&Bs[nxt][sB1] = rB1[nxt];
            *(bf16x8*)&Bs[nxt][sB2] = rB2[nxt];
            __syncthreads();
        }
    }

    // epilogue: lane holds gates for j = g*16 + c, rows m0 + wm*16 + (lane>>4)*4 + r
    int c = lane & 15, r0q = (lane >> 4) * 4;
    int g = n0 / 48 + wn;
    int j = g * 16 + c;
    float br = bhhp[g*48 + c]      + bihp[g*48 + c];
    float bz = bhhp[g*48 + 16 + c] + bihp[g*48 + 16 + c];
    float bn_h = bhhp[g*48 + 32 + c], bn_i = bihp[g*48 + 32 + c];
    #pragma unroll
    for (int r = 0; r < 4; r++) {
        int row = m0 + wm*16 + r0q + r;
        float rr = 1.f/(1.f + __expf(-(acc0[r] + br)));
        float zz = 1.f/(1.f + __expf(-(acc1[r] + bz)));
        float nn = tanhf(acc3[r] + bn_i + rr * (acc2[r] + bn_h));
        float hp = hprevf[(size_t)row*KP_G + j];
        float h = (1.f - zz)*nn + zz*hp;
        hnextf[(size_t)row*KP_G + j] = h;
        hb_out[(size_t)row*KP_G + j] = f2bf(h);
    }
}

// ================= per-(t,b) outputs, b-major grid for encf locality ========
__global__ void output_kernel(const float* __restrict__ pf, const float* __restrict__ encf,
                              const float* __restrict__ W_copy, const float* __restrict__ b_copy,
                              float* __restrict__ out) {
    __shared__ float sf[100];
    __shared__ float swc[100];
    __shared__ float scp[104];
    __shared__ float smx[4], ssx[4], smy[4], ssy[4];
    int bid = blockIdx.x;
    int b = bid / Tt, t = bid % Tt;     // consecutive blocks share b -> encf L2 hits
    int row = t*256 + b;
    int tid = threadIdx.x, lane = tid & 63, wv = tid >> 6;
    const float* pr = pf + (size_t)row * 384;
    if (tid < 100) { sf[tid] = pr[256 + tid]; swc[tid] = W_copy[tid]; }
    float x = (tid < 248) ? pr[tid] : -1e30f;
    if (tid == 247) scp[100] = x;       // eos into copy slot
    __syncthreads();                    // A: sf/swc ready
    const float* efb = encf + (size_t)b*Ll*128;
    for (int l = wv; l < Ll; l += 4) {
        const float* ef = efb + (size_t)l*128;
        float pp = selu_f(sf[lane] + ef[lane]) * swc[lane];
        if (lane < 36) pp += selu_f(sf[lane+64] + ef[lane+64]) * swc[lane+64];
        #pragma unroll
        for (int off = 32; off > 0; off >>= 1) pp += __shfl_down(pp, off);
        if (lane == 0) scp[l] = pp + b_copy[0];
    }
    float mx = x;
    #pragma unroll
    for (int off = 32; off > 0; off >>= 1) mx = fmaxf(mx, __shfl_xor(mx, off));
    if (lane == 0) smx[wv] = mx;
    __syncthreads();                    // B: scp + smx ready
    float m_x = fmaxf(fmaxf(smx[0], smx[1]), fmaxf(smx[2], smx[3]));
    float ex = (tid < 248) ? __expf(x - m_x) : 0.f;
    float sx = ex;
    #pragma unroll
    for (int off = 32; off > 0; off >>= 1) sx += __shfl_xor(sx, off);
    if (lane == 0) ssx[wv] = sx;
    float y = (tid < 101) ? scp[tid] : -1e30f;
    float my = y;
    #pragma unroll
    for (int off = 32; off > 0; off >>= 1) my = fmaxf(my, __shfl_xor(my, off));
    if (lane == 0) smy[wv] = my;
    __syncthreads();                    // C
    float* ob = out + (size_t)row*OUTW;
    float lse_x = m_x + __logf(ssx[0] + ssx[1] + ssx[2] + ssx[3]);
    if (tid < 248) ob[tid] = x - lse_x;
    float m_y = fmaxf(fmaxf(smy[0], smy[1]), fmaxf(smy[2], smy[3]));
    float ey = (tid < 101) ? __expf(y - m_y) : 0.f;
    float sy = ey;
    #pragma unroll
    for (int off = 32; off > 0; off >>= 1) sy += __shfl_xor(sy, off);
    if (lane == 0) ssy[wv] = sy;
    __syncthreads();                    // D
    float lse_y = m_y + __logf(ssy[0] + ssy[1] + ssy[2] + ssy[3]);
    if (tid < 101) ob[248 + tid] = y - lse_y;
}

// ============================================================================
extern "C" void kernel_launch(void* const* d_in, const int* in_sizes, int n_in,
                              void* d_out, int out_size, void* d_ws, size_t ws_size,
                              hipStream_t stream) {
    const float* emb    = (const float*)d_in[0];
    const float* enc    = (const float*)d_in[1];
    const float* conv   = (const float*)d_in[2];
    const float* h0     = (const float*)d_in[3];
    const float* W_attn = (const float*)d_in[4];
    const float* W_comb = (const float*)d_in[6];
    const float* b_comb = (const float*)d_in[7];
    const float* W_ih   = (const float*)d_in[8];
    const float* W_hh   = (const float*)d_in[9];
    const float* b_ih   = (const float*)d_in[10];
    const float* b_hh   = (const float*)d_in[11];
    const float* W_eos  = (const float*)d_in[12];
    const float* b_eos  = (const float*)d_in[13];
    const float* W_pred = (const float*)d_in[14];
    const float* b_pred = (const float*)d_in[15];
    const float* W_fuse = (const float*)d_in[16];
    const float* b_fuse = (const float*)d_in[17];
    const float* W_copy = (const float*)d_in[18];
    const float* b_copy = (const float*)d_in[19];
    float* out = (float*)d_out;

    char* p = (char*)d_ws;
    auto alloc = [&](size_t bytes) -> void* {
        void* r = (void*)p; p += (bytes + 255) & ~(size_t)255; return r;
    };
    float* pss    = (float*)alloc((size_t)Bb*12*4);
    float* pc     = (float*)alloc((size_t)Bb*12*1000*4);
    unsigned short* x_allb = (unsigned short*)alloc((size_t)Tt*Bb*KP_E*2);
    float* encf   = (float*)alloc((size_t)Bb*Ll*128*4);
    unsigned short* Wp     = (unsigned short*)alloc((size_t)NCP*KP_G*2);
    unsigned short* Wihpb  = (unsigned short*)alloc((size_t)NCP*KP_E*2);
    unsigned short* Wheads = (unsigned short*)alloc((size_t)384*KP_G*2);
    unsigned short* Wfb    = (unsigned short*)alloc((size_t)128*KP_G*2);
    float* bhhp     = (float*)alloc(NCP*4);
    float* bihp     = (float*)alloc(NCP*4);
    float* bias384  = (float*)alloc(384*4);
    float* bfuse128 = (float*)alloc(128*4);
    float* h_f[2];
    h_f[0] = (float*)alloc((size_t)Bb*KP_G*4);
    h_f[1] = (float*)alloc((size_t)Bb*KP_G*4);
    float* h0f = (float*)alloc((size_t)Bb*KP_G*4);
    unsigned short* h0b    = (unsigned short*)alloc((size_t)Bb*KP_G*2);
    unsigned short* hb_all = (unsigned short*)alloc((size_t)Tt*Bb*KP_G*2);
    float* pf = (float*)alloc((size_t)Tt*Bb*384*4);

    // ---- attention + ALL packing in ONE dispatch (independent work overlaps) ----
    attn_pack<<<3072 + 5260, 256, 0, stream>>>(
        enc, conv, W_attn + Hh, pss, pc,
        W_hh, W_ih, W_pred, W_fuse, h0, b_hh, b_ih, b_pred, b_eos, W_eos, b_fuse,
        Wp, Wihpb, Wheads, Wfb, h0b, h0f, bhhp, bihp, bias384, bfuse128);
    fused_ctx<<<Bb, 256, 0, stream>>>(pss, pc, W_comb, b_comb, emb, x_allb);

    // ---- serial GRU: R9-proven 2-deep-pipelined LDS kernel per step ----
    const unsigned short* hbprev = h0b;
    const float* hprev = h0f;
    for (int t = 0; t < Tt; ++t) {
        float* hnext = h_f[t & 1];
        unsigned short* hbnext = hb_all + (size_t)t*Bb*KP_G;
        gru_step<<<dim3(32, 8), 256, 0, stream>>>(hbprev, x_allb + (size_t)t*Bb*KP_E,
                                                  Wp, Wihpb, bhhp, bihp,
                                                  hprev, hnext, hbnext);
        hbprev = hbnext; hprev = hnext;
    }

    // ---- heads GEMM (t,b batched) + encf GEMM in ONE launch (580 blocks) ----
    heads_encf<<<580, 256, 0, stream>>>(hb_all, Wheads, bias384, pf, enc, Wfb, bfuse128, encf);
    output_kernel<<<Tt*Bb, 256, 0, stream>>>(pf, encf, W_copy, b_copy, out);
}

// Round 12
// 396.686 us; speedup vs baseline: 1.4274x; 1.0401x over previous
//
#include <hip/hip_runtime.h>
#include <hip/hip_bf16.h>
#include <math.h>

#define SELU_ALPHA 1.6732632423543772f
#define SELU_SCALE 1.0507009873554805f

typedef __attribute__((ext_vector_type(8))) short bf16x8;
typedef __attribute__((ext_vector_type(4))) float f32x4;

__device__ __forceinline__ float selu_f(float x) {
    return x > 0.f ? SELU_SCALE * x : SELU_SCALE * SELU_ALPHA * (__expf(x) - 1.f);
}
__device__ __forceinline__ unsigned short f2bf(float f) {
    __hip_bfloat16 h = __float2bfloat16(f);
    return *(unsigned short*)&h;
}
__device__ __forceinline__ float bf2f(unsigned short u) {
    unsigned int x = ((unsigned int)u) << 16;
    float f; __builtin_memcpy(&f, &x, 4); return f;
}

constexpr int Bb = 256, Ll = 100, Hh = 1000, Ee = 100, Rr = 247, Tt = 15;
constexpr int KP_G = 1024;             // padded K for H-sized bf16 GEMMs
constexpr int KP_E = 128;              // padded K for E-sized x rows
constexpr int NCP = 3072;              // packed gate cols: 64 groups x 48 (r16|z16|n16)
constexpr int OUTW = Rr + 1 + Ll + 1;  // 349

// map packed col n' -> (part, j).  g=n'/48, rem=n'%48, part=rem/16, c=rem%16, j=g*16+c
__device__ __forceinline__ void unpack_col(int np, int& part, int& j) {
    int g = np / 48, rem = np % 48;
    part = rem >> 4;
    j = g * 16 + (rem & 15);
}

// ======== merged: attention (blocks 0..3071) + ALL weight packing ===========
// attn: id = b*12 + ch; ch 0..3 enc (chunk 25), 4..11 conv (chunk 31).
// Barrier-free per-wave rows; softmax via fixed shift exp(s-8) (scores |s|<~8).
__launch_bounds__(256)
__global__ void attn_pack(const float* __restrict__ enc, const float* __restrict__ conv,
                          const float* __restrict__ Wb,
                          float* __restrict__ part_ss, float* __restrict__ part_ctx,
                          const float* __restrict__ W_hh, const float* __restrict__ W_ih,
                          const float* __restrict__ W_pred, const float* __restrict__ W_fuse,
                          const float* __restrict__ h0, const float* __restrict__ b_hh,
                          const float* __restrict__ b_ih, const float* __restrict__ b_pred,
                          const float* __restrict__ b_eos, const float* __restrict__ W_eos,
                          const float* __restrict__ b_fuse,
                          unsigned short* __restrict__ Wp, unsigned short* __restrict__ Wihpb,
                          unsigned short* __restrict__ Wheads, unsigned short* __restrict__ Wfb,
                          unsigned short* __restrict__ h0b, float* __restrict__ h0f,
                          float* __restrict__ bhhp, float* __restrict__ bihp,
                          float* __restrict__ bias384, float* __restrict__ bfuse128) {
    __shared__ float4 sbuf4[4 * 256];     // attn: per-wave ctx partials (16 KB)
    __shared__ float sredA[4];
    int id = blockIdx.x, tid = threadIdx.x;
    int lane = tid & 63, wv = tid >> 6;
    if (id < 3072) {
        // ---------------- attention ----------------
        int b = id / 12, ch = id % 12;
        const float* mem; int Nmem, l0, csz;
        if (ch < 4) { mem = enc;  Nmem = Ll; csz = 25; l0 = ch * 25; }
        else        { mem = conv; Nmem = Rr; csz = 31; l0 = (ch - 4) * 31; }
        int l1 = min(Nmem, l0 + csz);
        const float4* Wb4 = (const float4*)Wb;
        float4 w4[4];
        #pragma unroll
        for (int it = 0; it < 4; ++it) {
            int idx = lane + it*64;
            w4[it] = (idx < 250) ? Wb4[idx] : (float4){0.f,0.f,0.f,0.f};
        }
        float4 cx[4] = {{0,0,0,0},{0,0,0,0},{0,0,0,0},{0,0,0,0}};
        float ssum = 0.f;
        const float* base = mem + (size_t)b * Nmem * 1000;
        for (int l = l0 + wv; l < l1; l += 4) {
            const float4* r4 = (const float4*)(base + (size_t)l * 1000);
            float4 v[4];
            float s = 0.f;
            #pragma unroll
            for (int it = 0; it < 4; ++it) {
                int idx = lane + it*64;
                v[it] = (idx < 250) ? r4[idx] : (float4){0.f,0.f,0.f,0.f};
                s += v[it].x*w4[it].x + v[it].y*w4[it].y + v[it].z*w4[it].z + v[it].w*w4[it].w;
            }
            #pragma unroll
            for (int off = 32; off > 0; off >>= 1) s += __shfl_xor(s, off);
            float wgt = __expf(s - 8.f);
            ssum += wgt;
            #pragma unroll
            for (int it = 0; it < 4; ++it) {
                cx[it].x += wgt*v[it].x; cx[it].y += wgt*v[it].y;
                cx[it].z += wgt*v[it].z; cx[it].w += wgt*v[it].w;
            }
        }
        #pragma unroll
        for (int it = 0; it < 4; ++it) sbuf4[wv*256 + lane + it*64] = cx[it];
        if (lane == 0) sredA[wv] = ssum;
        __syncthreads();
        if (tid < 250) {
            float4 a0 = sbuf4[tid], a1 = sbuf4[256+tid], a2 = sbuf4[512+tid], a3 = sbuf4[768+tid];
            float4 acc = {a0.x+a1.x+a2.x+a3.x, a0.y+a1.y+a2.y+a3.y,
                          a0.z+a1.z+a2.z+a3.z, a0.w+a1.w+a2.w+a3.w};
            *(float4*)(part_ctx + (size_t)id * 1000 + tid*4) = acc;
        }
        if (tid == 0) part_ss[id] = sredA[0] + sredA[1] + sredA[2] + sredA[3];
        return;
    }
    // ---------------- weight packing ----------------
    float (*tile)[33] = (float(*)[33])sbuf4;
    int id2 = id - 3072;
    int tx = tid & 31, ty = tid >> 5;
    if (id2 < 3072) {                        // W_hh -> Wp (packed gates, transposed)
        int k0 = (id2 & 31) * 32, n0v = (id2 >> 5) * 32;
        for (int i = ty; i < 32; i += 8) {
            int k = k0 + i, np = n0v + tx;
            int part, j; unpack_col(np, part, j);
            tile[i][tx] = (k < Hh && j < Hh) ? W_hh[(size_t)k*3000 + part*1000 + j] : 0.f;
        }
        __syncthreads();
        for (int i = ty; i < 32; i += 8) {
            int np = n0v + i, k = k0 + tx;
            Wp[(size_t)np*KP_G + k] = f2bf(tile[tx][i]);
        }
    } else if (id2 < 3456) {                 // W_ih -> Wihpb
        int lid = id2 - 3072;
        int k0 = (lid & 3) * 32, n0v = (lid >> 2) * 32;
        for (int i = ty; i < 32; i += 8) {
            int k = k0 + i, np = n0v + tx;
            int part, j; unpack_col(np, part, j);
            tile[i][tx] = (k < Ee && j < Hh) ? W_ih[(size_t)k*3000 + part*1000 + j] : 0.f;
        }
        __syncthreads();
        for (int i = ty; i < 32; i += 8) {
            int np = n0v + i, k = k0 + tx;
            Wihpb[(size_t)np*KP_E + k] = f2bf(tile[tx][i]);
        }
    } else if (id2 < 4224) {                 // W_pred / W_fuse transposes
        int lid = id2 - 3456;
        int z = lid >> 8; int rem = lid & 255;
        int k0 = (rem & 31) * 32, n0v = (rem >> 5) * 32;
        const float* src; int srcLd, nValid, row0; unsigned short* dst; int nRows;
        if (z == 0)      { src = W_pred; srcLd = 247; nValid = 247; row0 = 0;    dst = Wheads;                    nRows = 256; }
        else if (z == 1) { if (n0v >= 128) return;
                           src = W_fuse; srcLd = 100; nValid = 100; row0 = 0;    dst = Wheads + (size_t)256*KP_G; nRows = 128; }
        else             { if (n0v >= 128) return;
                           src = W_fuse; srcLd = 100; nValid = 100; row0 = 1000; dst = Wfb;                       nRows = 128; }
        for (int i = ty; i < 32; i += 8) {
            int k = k0 + i, n = n0v + tx;
            tile[i][tx] = (k < Hh && n < nValid) ? src[(size_t)(row0 + k)*srcLd + n] : 0.f;
        }
        __syncthreads();
        for (int i = ty; i < 32; i += 8) {
            int n = n0v + i, k = k0 + tx;
            if (n < nRows && !(z == 0 && n == 247))   // row 247 owned by misc seg (eos)
                dst[(size_t)n*KP_G + k] = f2bf(tile[tx][i]);
        }
    } else {                                // h0 cvt + bias packing
        int bid2 = id2 - 4224;
        if (bid2 < 1024) {
            int i = bid2*256 + tid;
            int bb = i >> 10, j = i & 1023;
            float v = (j < Hh) ? h0[(size_t)bb*Hh + j] : 0.f;
            h0b[i] = f2bf(v);
            h0f[i] = v;
        } else {
            int i = (bid2 - 1024)*256 + tid;
            if (i < NCP) {
                int part, j; unpack_col(i, part, j);
                bhhp[i] = (j < Hh) ? b_hh[part*1000 + j] : 0.f;
                bihp[i] = (j < Hh) ? b_ih[part*1000 + j] : 0.f;
            }
            if (i < 384) bias384[i] = (i < 247) ? b_pred[i] : (i == 247 ? b_eos[0] : 0.f);
            if (i < 128) bfuse128[i] = (i < 100) ? b_fuse[i] : 0.f;
            if (i < KP_G) Wheads[(size_t)247*KP_G + i] = f2bf(i < Hh ? W_eos[i] : 0.f);
        }
    }
}

// ========== fused: combine partials -> contexts -> xc/xrc -> x_allb =========
// one block per batch b; partials are plain sums (uniform shift) -> just divide
__launch_bounds__(256)
__global__ void fused_ctx(const float* __restrict__ pss, const float* __restrict__ pc,
                          const float* __restrict__ W_comb, const float* __restrict__ b_comb,
                          const float* __restrict__ emb, unsigned short* __restrict__ x_allb) {
    __shared__ float sc[1000];
    __shared__ float srd[1000];
    __shared__ float sWt[10000];   // W_comb top 100x100
    __shared__ float semb[1500];   // emb[b] 15x100
    __shared__ float sxc[100], sxrc[100];
    int b = blockIdx.x, tid = threadIdx.x;
    float te = 0.f, tc = 0.f;
    #pragma unroll
    for (int c = 0; c < 4; ++c) te += pss[b*12 + c];
    #pragma unroll
    for (int c = 0; c < 8; ++c) tc += pss[b*12 + 4 + c];
    float ive = 1.f/te, ivc = 1.f/tc;
    if (tid < 250) {
        float4 aE = {0,0,0,0}, aC = {0,0,0,0};
        #pragma unroll
        for (int c = 0; c < 4; ++c) {
            float4 v = *(const float4*)(pc + (size_t)(b*12 + c)*1000 + tid*4);
            aE.x += v.x; aE.y += v.y; aE.z += v.z; aE.w += v.w;
        }
        #pragma unroll
        for (int c = 0; c < 8; ++c) {
            float4 v = *(const float4*)(pc + (size_t)(b*12 + 4 + c)*1000 + tid*4);
            aC.x += v.x; aC.y += v.y; aC.z += v.z; aC.w += v.w;
        }
        aE.x *= ive; aE.y *= ive; aE.z *= ive; aE.w *= ive;
        aC.x *= ivc; aC.y *= ivc; aC.z *= ivc; aC.w *= ivc;
        *(float4*)&sc[tid*4]  = aE;
        *(float4*)&srd[tid*4] = aC;
    }
    for (int i = tid; i < 10000; i += 256) sWt[i] = W_comb[i];           // rows 0..99
    for (int i = tid; i < 1500;  i += 256) semb[i] = emb[(size_t)b*1500 + i];
    __syncthreads();
    if (tid < 100) {
        float a0 = 0.f, a1 = 0.f;
        #pragma unroll 4
        for (int k = 0; k < 1000; ++k) {
            float w = W_comb[(size_t)(100 + k)*100 + tid];
            a0 += sc[k]*w; a1 += srd[k]*w;
        }
        sxc[tid]  = a0 + b_comb[tid];
        sxrc[tid] = a1 + b_comb[tid];
    }
    __syncthreads();
    #pragma unroll
    for (int pass = 0; pass < 8; ++pass) {
        int t = pass*2 + (tid >> 7);
        int col = tid & 127;
        if (t < Tt) {
            float v = 0.f;
            if (col < 100) {
                float a = 0.f;
                #pragma unroll 4
                for (int k = 0; k < 100; ++k) a += semb[t*100 + k] * sWt[k*100 + col];
                v = a + ((t % 3 == 0) ? sxrc[col] : sxc[col]);
            }
            x_allb[((size_t)t*Bb + b)*KP_E + col] = f2bf(v);
        }
    }
}

// ================= bf16 MFMA GEMM body (shared by heads/encf) ================
// AMODE 1: A fp32 [M][1000], selu. AMODE 3: A bf16 [M][KTOT], selu iff n0>=seluStart.
template<int AMODE, int KTOT>
__device__ __forceinline__
void gemm_body(int m0, int n0, const void* __restrict__ Aptr,
               const unsigned short* __restrict__ Bt, const float* __restrict__ bias,
               float* __restrict__ C, int ldc, int seluStart,
               unsigned short* As, unsigned short* Bs) {
    constexpr int BK = 64, KP = 72;
    int tid = threadIdx.x;
    int lane = tid & 63, wid = tid >> 6;
    int wm = wid >> 1, wn = wid & 1;
    bool doSelu = (AMODE == 1) || (AMODE == 3 && n0 >= seluStart);
    f32x4 acc[2][4];
    #pragma unroll
    for (int i = 0; i < 2; i++)
        #pragma unroll
        for (int j = 0; j < 4; j++) acc[i][j] = (f32x4){0.f, 0.f, 0.f, 0.f};

    for (int k0 = 0; k0 < KTOT; k0 += BK) {
        #pragma unroll
        for (int e = 0; e < 2; ++e) {
            int idx = tid + e*256;
            int row = idx >> 3, kc = idx & 7;
            int k = k0 + kc*8;
            int rg = m0 + row;
            bf16x8 v;
            if (AMODE == 1) {
                if (k < Hh) {
                    const float4* p = (const float4*)((const float*)Aptr + (size_t)rg*Hh + k);
                    float4 x = p[0], y = p[1];
                    v[0]=(short)f2bf(selu_f(x.x)); v[1]=(short)f2bf(selu_f(x.y));
                    v[2]=(short)f2bf(selu_f(x.z)); v[3]=(short)f2bf(selu_f(x.w));
                    v[4]=(short)f2bf(selu_f(y.x)); v[5]=(short)f2bf(selu_f(y.y));
                    v[6]=(short)f2bf(selu_f(y.z)); v[7]=(short)f2bf(selu_f(y.w));
                } else {
                    #pragma unroll
                    for (int j = 0; j < 8; j++) v[j] = 0;
                }
            } else {
                v = *(const bf16x8*)((const unsigned short*)Aptr + (size_t)rg*KTOT + k);
                if (doSelu) {
                    #pragma unroll
                    for (int j = 0; j < 8; j++)
                        v[j] = (short)f2bf(selu_f(bf2f((unsigned short)v[j])));
                }
            }
            *(bf16x8*)(&As[row*KP + kc*8]) = v;
        }
        #pragma unroll
        for (int e = 0; e < 4; ++e) {
            int idx = tid + e*256;
            int row = idx >> 3, kc = idx & 7;
            bf16x8 v = *(const bf16x8*)(Bt + (size_t)(n0 + row)*KTOT + k0 + kc*8);
            *(bf16x8*)(&Bs[row*KP + kc*8]) = v;
        }
        __syncthreads();
        #pragma unroll
        for (int kk = 0; kk < 2; ++kk) {
            bf16x8 af[2], bfr[4];
            #pragma unroll
            for (int mi = 0; mi < 2; mi++)
                af[mi] = *(const bf16x8*)(&As[(wm*32 + mi*16 + (lane & 15))*KP + kk*32 + (lane >> 4)*8]);
            #pragma unroll
            for (int ni = 0; ni < 4; ni++)
                bfr[ni] = *(const bf16x8*)(&Bs[(wn*64 + ni*16 + (lane & 15))*KP + kk*32 + (lane >> 4)*8]);
            #pragma unroll
            for (int mi = 0; mi < 2; mi++)
                #pragma unroll
                for (int ni = 0; ni < 4; ni++)
                    acc[mi][ni] = __builtin_amdgcn_mfma_f32_16x16x32_bf16(af[mi], bfr[ni], acc[mi][ni], 0, 0, 0);
        }
        __syncthreads();
    }
    int cr = (lane >> 4) * 4, cc = lane & 15;
    #pragma unroll
    for (int mi = 0; mi < 2; mi++) {
        #pragma unroll
        for (int ni = 0; ni < 4; ni++) {
            int col = n0 + wn*64 + ni*16 + cc;
            float bv = bias ? bias[col] : 0.f;
            #pragma unroll
            for (int r = 0; r < 4; r++) {
                int row = m0 + wm*32 + mi*16 + cr + r;
                C[(size_t)row*ldc + col] = acc[mi][ni][r] + bv;
            }
        }
    }
}

// merged launch: blocks [0,180) = heads GEMM over all (t,b); [180,580) = encf GEMM
__launch_bounds__(256)
__global__ void heads_encf(const unsigned short* __restrict__ hb_all,
                           const unsigned short* __restrict__ Wheads,
                           const float* __restrict__ bias384, float* __restrict__ pf,
                           const float* __restrict__ enc, const unsigned short* __restrict__ Wfb,
                           const float* __restrict__ bfuse128, float* __restrict__ encf) {
    __shared__ unsigned short As[64 * 72];
    __shared__ unsigned short Bs[128 * 72];
    int id = blockIdx.x;
    if (id < 180) {
        int n0 = (id % 3) * 128, m0 = (id / 3) * 64;
        gemm_body<3, KP_G>(m0, n0, hb_all, Wheads, bias384, pf, 384, 256, As, Bs);
    } else {
        int m0 = (id - 180) * 64;
        gemm_body<1, KP_G>(m0, 0, enc, Wfb, bfuse128, encf, 128, 0, As, Bs);
    }
}

// ====== fused GRU step: (h@Whh + x@Wih) + gates; unrolled 3-deep pipeline ===
// grid (32, 8): n-tiles of 96 (2 gate-groups), m-tiles of 32. 4 waves (2m x 2n).
// 18 K-tiles of 64: tiles 0..15 from h/Wp, 16..17 from x/Wihpb — all branches
// compile-time via full unroll; loads issued 3 tiles ahead (mod-3 reg slots).
__launch_bounds__(256)
__global__ void gru_step(const unsigned short* __restrict__ hbA,
                         const unsigned short* __restrict__ xab,
                         const unsigned short* __restrict__ Wp,
                         const unsigned short* __restrict__ Wihpb,
                         const float* __restrict__ bhhp, const float* __restrict__ bihp,
                         const float* __restrict__ hprevf, float* __restrict__ hnextf,
                         unsigned short* __restrict__ hb_out) {
    constexpr int KP = 72;
    __shared__ unsigned short As[2][32 * KP];
    __shared__ unsigned short Bs[2][96 * KP];
    int tid = threadIdx.x, lane = tid & 63, wid = tid >> 6;
    int wm = wid >> 1, wn = wid & 1;
    int n0 = blockIdx.x * 96, m0 = blockIdx.y * 32;
    int sr = tid >> 3, skc = tid & 7;

    const unsigned short* hA  = hbA + (size_t)(m0+sr)*KP_G + skc*8;
    const unsigned short* xA  = xab + (size_t)(m0+sr)*KP_E + skc*8;
    const unsigned short* wp0 = Wp  + (size_t)(n0+sr)*KP_G + skc*8;
    const unsigned short* wp1 = wp0 + (size_t)32*KP_G;
    const unsigned short* wp2 = wp0 + (size_t)64*KP_G;
    const unsigned short* wx0 = Wihpb + (size_t)(n0+sr)*KP_E + skc*8;
    const unsigned short* wx1 = wx0 + (size_t)32*KP_E;
    const unsigned short* wx2 = wx0 + (size_t)64*KP_E;

    auto loadT = [&](int t, bf16x8& ra, bf16x8& b0, bf16x8& b1, bf16x8& b2) {
        if (t < 16) {
            int k = t*64;
            ra = *(const bf16x8*)(hA  + k);
            b0 = *(const bf16x8*)(wp0 + k);
            b1 = *(const bf16x8*)(wp1 + k);
            b2 = *(const bf16x8*)(wp2 + k);
        } else {
            int k = (t-16)*64;
            ra = *(const bf16x8*)(xA  + k);
            b0 = *(const bf16x8*)(wx0 + k);
            b1 = *(const bf16x8*)(wx1 + k);
            b2 = *(const bf16x8*)(wx2 + k);
        }
    };
    int sA = sr*KP + skc*8;
    int sB0 = sA, sB1 = (sr+32)*KP + skc*8, sB2 = (sr+64)*KP + skc*8;

    f32x4 acc0 = {0,0,0,0}, acc1 = {0,0,0,0}, acc2 = {0,0,0,0}, acc3 = {0,0,0,0};

    bf16x8 rA[3], rB0[3], rB1[3], rB2[3];
    // prologue: tile 0 -> LDS[0]; tiles 1,2 -> reg slots 1,2
    loadT(0, rA[0], rB0[0], rB1[0], rB2[0]);
    *(bf16x8*)&As[0][sA]  = rA[0];
    *(bf16x8*)&Bs[0][sB0] = rB0[0];
    *(bf16x8*)&Bs[0][sB1] = rB1[0];
    *(bf16x8*)&Bs[0][sB2] = rB2[0];
    loadT(1, rA[1], rB0[1], rB1[1], rB2[1]);
    loadT(2, rA[2], rB0[2], rB1[2], rB2[2]);
    __syncthreads();

    int aoff  = (wm*16 + (lane & 15))*KP + (lane >> 4)*8;
    int boff0 = (wn*48 + (lane & 15))*KP + (lane >> 4)*8;
    int boff1 = boff0 + 16*KP, boff2 = boff0 + 32*KP;

    #pragma unroll
    for (int t = 0; t < 18; ++t) {
        int cur = t & 1, nxt = cur ^ 1;
        int sl = t % 3;            // slot holding tile t (already in LDS) -> reuse for t+3
        int sw = (t + 1) % 3;      // slot holding tile t+1
        if (t + 3 < 18) loadT(t+3, rA[sl], rB0[sl], rB1[sl], rB2[sl]);
        #pragma unroll
        for (int kk = 0; kk < 2; ++kk) {
            bf16x8 af = *(const bf16x8*)(&As[cur][aoff + kk*32]);
            acc0 = __builtin_amdgcn_mfma_f32_16x16x32_bf16(af, *(const bf16x8*)(&Bs[cur][boff0 + kk*32]), acc0, 0, 0, 0);
            acc1 = __builtin_amdgcn_mfma_f32_16x16x32_bf16(af, *(const bf16x8*)(&Bs[cur][boff1 + kk*32]), acc1, 0, 0, 0);
            bf16x8 b2v = *(const bf16x8*)(&Bs[cur][boff2 + kk*32]);
            if (t < 16) acc2 = __builtin_amdgcn_mfma_f32_16x16x32_bf16(af, b2v, acc2, 0, 0, 0);
            else        acc3 = __builtin_amdgcn_mfma_f32_16x16x32_bf16(af, b2v, acc3, 0, 0, 0);
        }
        if (t + 1 < 18) {
            *(bf16x8*)&As[nxt][sA]  = rA[sw];
            *(bf16x8*)&Bs[nxt][sB0] = rB0[sw];
            *(bf16x8*)&Bs[nxt][sB1] = rB1[sw];
            *(bf16x8*)&Bs[nxt][sB2] = rB2[sw];
            __syncthreads();
        }
    }

    // epilogue: lane holds gates for j = g*16 + c, rows m0 + wm*16 + (lane>>4)*4 + r
    int c = lane & 15, r0q = (lane >> 4) * 4;
    int g = n0 / 48 + wn;
    int j = g * 16 + c;
    float br = bhhp[g*48 + c]      + bihp[g*48 + c];
    float bz = bhhp[g*48 + 16 + c] + bihp[g*48 + 16 + c];
    float bn_h = bhhp[g*48 + 32 + c], bn_i = bihp[g*48 + 32 + c];
    #pragma unroll
    for (int r = 0; r < 4; r++) {
        int row = m0 + wm*16 + r0q + r;
        float rr = 1.f/(1.f + __expf(-(acc0[r] + br)));
        float zz = 1.f/(1.f + __expf(-(acc1[r] + bz)));
        float nn = tanhf(acc3[r] + bn_i + rr * (acc2[r] + bn_h));
        float hp = hprevf[(size_t)row*KP_G + j];
        float h = (1.f - zz)*nn + zz*hp;
        hnextf[(size_t)row*KP_G + j] = h;
        hb_out[(size_t)row*KP_G + j] = f2bf(h);
    }
}

// ================= per-(b, 4t) outputs: encf loaded once per 4 t's ==========
// grid 1024: b = bid>>2, tq = bid&3; t = tq*4 + i. Softmax phase: one wave per t.
__launch_bounds__(256)
__global__ void output_kernel(const float* __restrict__ pf, const float* __restrict__ encf,
                              const float* __restrict__ W_copy, const float* __restrict__ b_copy,
                              float* __restrict__ out) {
    __shared__ float sf[4][100];
    __shared__ float swc[100];
    __shared__ float scp[4][104];
    int bid = blockIdx.x;
    int b = bid >> 2, tq = bid & 3;
    int t0 = tq * 4;
    int nt = min(4, Tt - t0);                 // 4,4,4,3
    int tid = threadIdx.x, lane = tid & 63, wv = tid >> 6;
    if (tid < 100) {
        swc[tid] = W_copy[tid];
        for (int i = 0; i < nt; ++i)
            sf[i][tid] = pf[(size_t)((t0 + i)*256 + b) * 384 + 256 + tid];
    }
    __syncthreads();
    const float* efb = encf + (size_t)b*Ll*128;
    float bcp = b_copy[0];
    float w0 = swc[lane];
    float w1 = (lane < 36) ? swc[lane+64] : 0.f;
    for (int l = wv; l < Ll; l += 4) {
        const float* ef = efb + (size_t)l*128;
        float e0 = ef[lane];
        float e1 = (lane < 36) ? ef[lane+64] : 0.f;
        #pragma unroll
        for (int i = 0; i < 4; ++i) {
            if (i >= nt) break;
            float pp = selu_f(sf[i][lane] + e0) * w0;
            if (lane < 36) pp += selu_f(sf[i][lane+64] + e1) * w1;
            #pragma unroll
            for (int off = 32; off > 0; off >>= 1) pp += __shfl_down(pp, off);
            if (lane == 0) scp[i][l] = pp + bcp;
        }
    }
    __syncthreads();
    // one wave per t: fully in-wave log-softmaxes
    if (wv < nt) {
        int t = t0 + wv;
        int row = t*256 + b;
        const float* pr = pf + (size_t)row * 384;
        float* ob = out + (size_t)row * OUTW;
        // pred log-softmax over 248 (= 3*64 + 56)
        float x0 = pr[lane];
        float x1 = pr[lane + 64];
        float x2 = pr[lane + 128];
        float x3 = (lane < 56) ? pr[lane + 192] : -1e30f;
        float eos = pr[247];
        float mx = fmaxf(fmaxf(x0, x1), fmaxf(x2, x3));
        #pragma unroll
        for (int off = 32; off > 0; off >>= 1) mx = fmaxf(mx, __shfl_xor(mx, off));
        float s = __expf(x0 - mx) + __expf(x1 - mx) + __expf(x2 - mx)
                + ((lane < 56) ? __expf(x3 - mx) : 0.f);
        #pragma unroll
        for (int off = 32; off > 0; off >>= 1) s += __shfl_xor(s, off);
        float lse = mx + __logf(s);
        ob[lane]       = x0 - lse;
        ob[lane + 64]  = x1 - lse;
        ob[lane + 128] = x2 - lse;
        if (lane < 56) ob[lane + 192] = x3 - lse;
        // copy log-softmax over 101 (= 64 + 36 + eos)
        float y0 = scp[wv][lane];
        float y1 = (lane < 36) ? scp[wv][lane + 64] : -1e30f;
        float my = fmaxf(y0, fmaxf(y1, eos));
        #pragma unroll
        for (int off = 32; off > 0; off >>= 1) my = fmaxf(my, __shfl_xor(my, off));
        float sy = __expf(y0 - my) + ((lane < 36) ? __expf(y1 - my) : 0.f)
                 + ((lane == 0) ? __expf(eos - my) : 0.f);
        #pragma unroll
        for (int off = 32; off > 0; off >>= 1) sy += __shfl_xor(sy, off);
        float lsey = my + __logf(sy);
        ob[248 + lane] = y0 - lsey;
        if (lane < 36) ob[248 + 64 + lane] = y1 - lsey;
        if (lane == 0) ob[248 + 100] = eos - lsey;
    }
}

// ============================================================================
extern "C" void kernel_launch(void* const* d_in, const int* in_sizes, int n_in,
                              void* d_out, int out_size, void* d_ws, size_t ws_size,
                              hipStream_t stream) {
    const float* emb    = (const float*)d_in[0];
    const float* enc    = (const float*)d_in[1];
    const float* conv   = (const float*)d_in[2];
    const float* h0     = (const float*)d_in[3];
    const float* W_attn = (const float*)d_in[4];
    const float* W_comb = (const float*)d_in[6];
    const float* b_comb = (const float*)d_in[7];
    const float* W_ih   = (const float*)d_in[8];
    const float* W_hh   = (const float*)d_in[9];
    const float* b_ih   = (const float*)d_in[10];
    const float* b_hh   = (const float*)d_in[11];
    const float* W_eos  = (const float*)d_in[12];
    const float* b_eos  = (const float*)d_in[13];
    const float* W_pred = (const float*)d_in[14];
    const float* b_pred = (const float*)d_in[15];
    const float* W_fuse = (const float*)d_in[16];
    const float* b_fuse = (const float*)d_in[17];
    const float* W_copy = (const float*)d_in[18];
    const float* b_copy = (const float*)d_in[19];
    float* out = (float*)d_out;

    char* p = (char*)d_ws;
    auto alloc = [&](size_t bytes) -> void* {
        void* r = (void*)p; p += (bytes + 255) & ~(size_t)255; return r;
    };
    float* pss    = (float*)alloc((size_t)Bb*12*4);
    float* pc     = (float*)alloc((size_t)Bb*12*1000*4);
    unsigned short* x_allb = (unsigned short*)alloc((size_t)Tt*Bb*KP_E*2);
    float* encf   = (float*)alloc((size_t)Bb*Ll*128*4);
    unsigned short* Wp     = (unsigned short*)alloc((size_t)NCP*KP_G*2);
    unsigned short* Wihpb  = (unsigned short*)alloc((size_t)NCP*KP_E*2);
    unsigned short* Wheads = (unsigned short*)alloc((size_t)384*KP_G*2);
    unsigned short* Wfb    = (unsigned short*)alloc((size_t)128*KP_G*2);
    float* bhhp     = (float*)alloc(NCP*4);
    float* bihp     = (float*)alloc(NCP*4);
    float* bias384  = (float*)alloc(384*4);
    float* bfuse128 = (float*)alloc(128*4);
    float* h_f[2];
    h_f[0] = (float*)alloc((size_t)Bb*KP_G*4);
    h_f[1] = (float*)alloc((size_t)Bb*KP_G*4);
    float* h0f = (float*)alloc((size_t)Bb*KP_G*4);
    unsigned short* h0b    = (unsigned short*)alloc((size_t)Bb*KP_G*2);
    unsigned short* hb_all = (unsigned short*)alloc((size_t)Tt*Bb*KP_G*2);
    float* pf = (float*)alloc((size_t)Tt*Bb*384*4);

    // ---- attention + ALL packing in ONE dispatch (independent work overlaps) ----
    attn_pack<<<3072 + 5260, 256, 0, stream>>>(
        enc, conv, W_attn + Hh, pss, pc,
        W_hh, W_ih, W_pred, W_fuse, h0, b_hh, b_ih, b_pred, b_eos, W_eos, b_fuse,
        Wp, Wihpb, Wheads, Wfb, h0b, h0f, bhhp, bihp, bias384, bfuse128);
    fused_ctx<<<Bb, 256, 0, stream>>>(pss, pc, W_comb, b_comb, emb, x_allb);

    // ---- serial GRU: 3-deep-pipelined LDS kernel per step ----
    const unsigned short* hbprev = h0b;
    const float* hprev = h0f;
    for (int t = 0; t < Tt; ++t) {
        float* hnext = h_f[t & 1];
        unsigned short* hbnext = hb_all + (size_t)t*Bb*KP_G;
        gru_step<<<dim3(32, 8), 256, 0, stream>>>(hbprev, x_allb + (size_t)t*Bb*KP_E,
                                                  Wp, Wihpb, bhhp, bihp,
                                                  hprev, hnext, hbnext);
        hbprev = hbnext; hprev = hnext;
    }

    // ---- heads GEMM (t,b batched) + encf GEMM in ONE launch (580 blocks) ----
    heads_encf<<<580, 256, 0, stream>>>(hb_all, Wheads, bias384, pf, enc, Wfb, bfuse128, encf);
    output_kernel<<<1024, 256, 0, stream>>>(pf, encf, W_copy, b_copy, out);
}

// Round 13
// 390.576 us; speedup vs baseline: 1.4497x; 1.0156x over previous
//
#include <hip/hip_runtime.h>
#include <hip/hip_bf16.h>
#include <math.h>

#define SELU_ALPHA 1.6732632423543772f
#define SELU_SCALE 1.0507009873554805f

typedef __attribute__((ext_vector_type(8))) short bf16x8;
typedef __attribute__((ext_vector_type(4))) float f32x4;

__device__ __forceinline__ float selu_f(float x) {
    return x > 0.f ? SELU_SCALE * x : SELU_SCALE * SELU_ALPHA * (__expf(x) - 1.f);
}
__device__ __forceinline__ unsigned short f2bf(float f) {
    __hip_bfloat16 h = __float2bfloat16(f);
    return *(unsigned short*)&h;
}
__device__ __forceinline__ float bf2f(unsigned short u) {
    unsigned int x = ((unsigned int)u) << 16;
    float f; __builtin_memcpy(&f, &x, 4); return f;
}

constexpr int Bb = 256, Ll = 100, Hh = 1000, Ee = 100, Rr = 247, Tt = 15;
constexpr int KP_G = 1024;             // padded K for H-sized bf16 GEMMs
constexpr int KP_E = 128;              // padded K for E-sized x rows
constexpr int NCP = 3072;              // packed gate cols: 64 groups x 48 (r16|z16|n16)
constexpr int OUTW = Rr + 1 + Ll + 1;  // 349

// map packed col n' -> (part, j).  g=n'/48, rem=n'%48, part=rem/16, c=rem%16, j=g*16+c
__device__ __forceinline__ void unpack_col(int np, int& part, int& j) {
    int g = np / 48, rem = np % 48;
    part = rem >> 4;
    j = g * 16 + (rem & 15);
}

// ======== merged: attention (blocks 0..3071) + ALL weight packing ===========
// attn: id = b*12 + ch; ch 0..3 enc (chunk 25), 4..11 conv (chunk 31).
// Barrier-free per-wave rows; softmax via fixed shift exp(s-8) (scores |s|<~8).
__launch_bounds__(256)
__global__ void attn_pack(const float* __restrict__ enc, const float* __restrict__ conv,
                          const float* __restrict__ Wb,
                          float* __restrict__ part_ss, float* __restrict__ part_ctx,
                          const float* __restrict__ W_hh, const float* __restrict__ W_ih,
                          const float* __restrict__ W_pred, const float* __restrict__ W_fuse,
                          const float* __restrict__ h0, const float* __restrict__ b_hh,
                          const float* __restrict__ b_ih, const float* __restrict__ b_pred,
                          const float* __restrict__ b_eos, const float* __restrict__ W_eos,
                          const float* __restrict__ b_fuse,
                          unsigned short* __restrict__ Wp, unsigned short* __restrict__ Wihpb,
                          unsigned short* __restrict__ Wheads, unsigned short* __restrict__ Wfb,
                          unsigned short* __restrict__ h0b,
                          float* __restrict__ bhhp, float* __restrict__ bihp,
                          float* __restrict__ bias384, float* __restrict__ bfuse128) {
    __shared__ float4 sbuf4[4 * 256];     // attn: per-wave ctx partials (16 KB)
    __shared__ float sredA[4];
    int id = blockIdx.x, tid = threadIdx.x;
    int lane = tid & 63, wv = tid >> 6;
    if (id < 3072) {
        // ---------------- attention ----------------
        int b = id / 12, ch = id % 12;
        const float* mem; int Nmem, l0, csz;
        if (ch < 4) { mem = enc;  Nmem = Ll; csz = 25; l0 = ch * 25; }
        else        { mem = conv; Nmem = Rr; csz = 31; l0 = (ch - 4) * 31; }
        int l1 = min(Nmem, l0 + csz);
        const float4* Wb4 = (const float4*)Wb;
        float4 w4[4];
        #pragma unroll
        for (int it = 0; it < 4; ++it) {
            int idx = lane + it*64;
            w4[it] = (idx < 250) ? Wb4[idx] : (float4){0.f,0.f,0.f,0.f};
        }
        float4 cx[4] = {{0,0,0,0},{0,0,0,0},{0,0,0,0},{0,0,0,0}};
        float ssum = 0.f;
        const float* base = mem + (size_t)b * Nmem * 1000;
        for (int l = l0 + wv; l < l1; l += 4) {
            const float4* r4 = (const float4*)(base + (size_t)l * 1000);
            float4 v[4];
            float s = 0.f;
            #pragma unroll
            for (int it = 0; it < 4; ++it) {
                int idx = lane + it*64;
                v[it] = (idx < 250) ? r4[idx] : (float4){0.f,0.f,0.f,0.f};
                s += v[it].x*w4[it].x + v[it].y*w4[it].y + v[it].z*w4[it].z + v[it].w*w4[it].w;
            }
            #pragma unroll
            for (int off = 32; off > 0; off >>= 1) s += __shfl_xor(s, off);
            float wgt = __expf(s - 8.f);
            ssum += wgt;
            #pragma unroll
            for (int it = 0; it < 4; ++it) {
                cx[it].x += wgt*v[it].x; cx[it].y += wgt*v[it].y;
                cx[it].z += wgt*v[it].z; cx[it].w += wgt*v[it].w;
            }
        }
        #pragma unroll
        for (int it = 0; it < 4; ++it) sbuf4[wv*256 + lane + it*64] = cx[it];
        if (lane == 0) sredA[wv] = ssum;
        __syncthreads();
        if (tid < 250) {
            float4 a0 = sbuf4[tid], a1 = sbuf4[256+tid], a2 = sbuf4[512+tid], a3 = sbuf4[768+tid];
            float4 acc = {a0.x+a1.x+a2.x+a3.x, a0.y+a1.y+a2.y+a3.y,
                          a0.z+a1.z+a2.z+a3.z, a0.w+a1.w+a2.w+a3.w};
            *(float4*)(part_ctx + (size_t)id * 1000 + tid*4) = acc;
        }
        if (tid == 0) part_ss[id] = sredA[0] + sredA[1] + sredA[2] + sredA[3];
        return;
    }
    // ---------------- weight packing ----------------
    float (*tile)[33] = (float(*)[33])sbuf4;
    int id2 = id - 3072;
    int tx = tid & 31, ty = tid >> 5;
    if (id2 < 3072) {                        // W_hh -> Wp (packed gates, transposed)
        int k0 = (id2 & 31) * 32, n0v = (id2 >> 5) * 32;
        for (int i = ty; i < 32; i += 8) {
            int k = k0 + i, np = n0v + tx;
            int part, j; unpack_col(np, part, j);
            tile[i][tx] = (k < Hh && j < Hh) ? W_hh[(size_t)k*3000 + part*1000 + j] : 0.f;
        }
        __syncthreads();
        for (int i = ty; i < 32; i += 8) {
            int np = n0v + i, k = k0 + tx;
            Wp[(size_t)np*KP_G + k] = f2bf(tile[tx][i]);
        }
    } else if (id2 < 3456) {                 // W_ih -> Wihpb
        int lid = id2 - 3072;
        int k0 = (lid & 3) * 32, n0v = (lid >> 2) * 32;
        for (int i = ty; i < 32; i += 8) {
            int k = k0 + i, np = n0v + tx;
            int part, j; unpack_col(np, part, j);
            tile[i][tx] = (k < Ee && j < Hh) ? W_ih[(size_t)k*3000 + part*1000 + j] : 0.f;
        }
        __syncthreads();
        for (int i = ty; i < 32; i += 8) {
            int np = n0v + i, k = k0 + tx;
            Wihpb[(size_t)np*KP_E + k] = f2bf(tile[tx][i]);
        }
    } else if (id2 < 4224) {                 // W_pred / W_fuse transposes
        int lid = id2 - 3456;
        int z = lid >> 8; int rem = lid & 255;
        int k0 = (rem & 31) * 32, n0v = (rem >> 5) * 32;
        const float* src; int srcLd, nValid, row0; unsigned short* dst; int nRows;
        if (z == 0)      { src = W_pred; srcLd = 247; nValid = 247; row0 = 0;    dst = Wheads;                    nRows = 256; }
        else if (z == 1) { if (n0v >= 128) return;
                           src = W_fuse; srcLd = 100; nValid = 100; row0 = 0;    dst = Wheads + (size_t)256*KP_G; nRows = 128; }
        else             { if (n0v >= 128) return;
                           src = W_fuse; srcLd = 100; nValid = 100; row0 = 1000; dst = Wfb;                       nRows = 128; }
        for (int i = ty; i < 32; i += 8) {
            int k = k0 + i, n = n0v + tx;
            tile[i][tx] = (k < Hh && n < nValid) ? src[(size_t)(row0 + k)*srcLd + n] : 0.f;
        }
        __syncthreads();
        for (int i = ty; i < 32; i += 8) {
            int n = n0v + i, k = k0 + tx;
            if (n < nRows && !(z == 0 && n == 247))   // row 247 owned by misc seg (eos)
                dst[(size_t)n*KP_G + k] = f2bf(tile[tx][i]);
        }
    } else {                                // h0 cvt + bias packing
        int bid2 = id2 - 4224;
        if (bid2 < 1024) {
            int i = bid2*256 + tid;
            int bb = i >> 10, j = i & 1023;
            h0b[i] = f2bf((j < Hh) ? h0[(size_t)bb*Hh + j] : 0.f);
        } else {
            int i = (bid2 - 1024)*256 + tid;
            if (i < NCP) {
                int part, j; unpack_col(i, part, j);
                bhhp[i] = (j < Hh) ? b_hh[part*1000 + j] : 0.f;
                bihp[i] = (j < Hh) ? b_ih[part*1000 + j] : 0.f;
            }
            if (i < 384) bias384[i] = (i < 247) ? b_pred[i] : (i == 247 ? b_eos[0] : 0.f);
            if (i < 128) bfuse128[i] = (i < 100) ? b_fuse[i] : 0.f;
            if (i < KP_G) Wheads[(size_t)247*KP_G + i] = f2bf(i < Hh ? W_eos[i] : 0.f);
        }
    }
}

// ========== fused: combine partials -> contexts -> xc/xrc -> x_allb =========
// one block per batch b; partials are plain sums (uniform shift) -> just divide
__launch_bounds__(256)
__global__ void fused_ctx(const float* __restrict__ pss, const float* __restrict__ pc,
                          const float* __restrict__ W_comb, const float* __restrict__ b_comb,
                          const float* __restrict__ emb, unsigned short* __restrict__ x_allb) {
    __shared__ float sc[1000];
    __shared__ float srd[1000];
    __shared__ float sWt[10000];   // W_comb top 100x100
    __shared__ float semb[1500];   // emb[b] 15x100
    __shared__ float sxc[100], sxrc[100];
    int b = blockIdx.x, tid = threadIdx.x;
    float te = 0.f, tc = 0.f;
    #pragma unroll
    for (int c = 0; c < 4; ++c) te += pss[b*12 + c];
    #pragma unroll
    for (int c = 0; c < 8; ++c) tc += pss[b*12 + 4 + c];
    float ive = 1.f/te, ivc = 1.f/tc;
    if (tid < 250) {
        float4 aE = {0,0,0,0}, aC = {0,0,0,0};
        #pragma unroll
        for (int c = 0; c < 4; ++c) {
            float4 v = *(const float4*)(pc + (size_t)(b*12 + c)*1000 + tid*4);
            aE.x += v.x; aE.y += v.y; aE.z += v.z; aE.w += v.w;
        }
        #pragma unroll
        for (int c = 0; c < 8; ++c) {
            float4 v = *(const float4*)(pc + (size_t)(b*12 + 4 + c)*1000 + tid*4);
            aC.x += v.x; aC.y += v.y; aC.z += v.z; aC.w += v.w;
        }
        aE.x *= ive; aE.y *= ive; aE.z *= ive; aE.w *= ive;
        aC.x *= ivc; aC.y *= ivc; aC.z *= ivc; aC.w *= ivc;
        *(float4*)&sc[tid*4]  = aE;
        *(float4*)&srd[tid*4] = aC;
    }
    for (int i = tid; i < 10000; i += 256) sWt[i] = W_comb[i];           // rows 0..99
    for (int i = tid; i < 1500;  i += 256) semb[i] = emb[(size_t)b*1500 + i];
    __syncthreads();
    if (tid < 100) {
        float a0 = 0.f, a1 = 0.f;
        #pragma unroll 4
        for (int k = 0; k < 1000; ++k) {
            float w = W_comb[(size_t)(100 + k)*100 + tid];
            a0 += sc[k]*w; a1 += srd[k]*w;
        }
        sxc[tid]  = a0 + b_comb[tid];
        sxrc[tid] = a1 + b_comb[tid];
    }
    __syncthreads();
    #pragma unroll
    for (int pass = 0; pass < 8; ++pass) {
        int t = pass*2 + (tid >> 7);
        int col = tid & 127;
        if (t < Tt) {
            float v = 0.f;
            if (col < 100) {
                float a = 0.f;
                #pragma unroll 4
                for (int k = 0; k < 100; ++k) a += semb[t*100 + k] * sWt[k*100 + col];
                v = a + ((t % 3 == 0) ? sxrc[col] : sxc[col]);
            }
            x_allb[((size_t)t*Bb + b)*KP_E + col] = f2bf(v);
        }
    }
}

// ================= bf16 MFMA GEMM body (shared by heads/encf) ================
// AMODE 1: A fp32 [M][1000], selu. AMODE 3: A bf16 [M][KTOT], selu iff n0>=seluStart.
template<int AMODE, int KTOT>
__device__ __forceinline__
void gemm_body(int m0, int n0, const void* __restrict__ Aptr,
               const unsigned short* __restrict__ Bt, const float* __restrict__ bias,
               float* __restrict__ C, int ldc, int seluStart,
               unsigned short* As, unsigned short* Bs) {
    constexpr int BK = 64, KP = 72;
    int tid = threadIdx.x;
    int lane = tid & 63, wid = tid >> 6;
    int wm = wid >> 1, wn = wid & 1;
    bool doSelu = (AMODE == 1) || (AMODE == 3 && n0 >= seluStart);
    f32x4 acc[2][4];
    #pragma unroll
    for (int i = 0; i < 2; i++)
        #pragma unroll
        for (int j = 0; j < 4; j++) acc[i][j] = (f32x4){0.f, 0.f, 0.f, 0.f};

    for (int k0 = 0; k0 < KTOT; k0 += BK) {
        #pragma unroll
        for (int e = 0; e < 2; ++e) {
            int idx = tid + e*256;
            int row = idx >> 3, kc = idx & 7;
            int k = k0 + kc*8;
            int rg = m0 + row;
            bf16x8 v;
            if (AMODE == 1) {
                if (k < Hh) {
                    const float4* p = (const float4*)((const float*)Aptr + (size_t)rg*Hh + k);
                    float4 x = p[0], y = p[1];
                    v[0]=(short)f2bf(selu_f(x.x)); v[1]=(short)f2bf(selu_f(x.y));
                    v[2]=(short)f2bf(selu_f(x.z)); v[3]=(short)f2bf(selu_f(x.w));
                    v[4]=(short)f2bf(selu_f(y.x)); v[5]=(short)f2bf(selu_f(y.y));
                    v[6]=(short)f2bf(selu_f(y.z)); v[7]=(short)f2bf(selu_f(y.w));
                } else {
                    #pragma unroll
                    for (int j = 0; j < 8; j++) v[j] = 0;
                }
            } else {
                v = *(const bf16x8*)((const unsigned short*)Aptr + (size_t)rg*KTOT + k);
                if (doSelu) {
                    #pragma unroll
                    for (int j = 0; j < 8; j++)
                        v[j] = (short)f2bf(selu_f(bf2f((unsigned short)v[j])));
                }
            }
            *(bf16x8*)(&As[row*KP + kc*8]) = v;
        }
        #pragma unroll
        for (int e = 0; e < 4; ++e) {
            int idx = tid + e*256;
            int row = idx >> 3, kc = idx & 7;
            bf16x8 v = *(const bf16x8*)(Bt + (size_t)(n0 + row)*KTOT + k0 + kc*8);
            *(bf16x8*)(&Bs[row*KP + kc*8]) = v;
        }
        __syncthreads();
        #pragma unroll
        for (int kk = 0; kk < 2; ++kk) {
            bf16x8 af[2], bfr[4];
            #pragma unroll
            for (int mi = 0; mi < 2; mi++)
                af[mi] = *(const bf16x8*)(&As[(wm*32 + mi*16 + (lane & 15))*KP + kk*32 + (lane >> 4)*8]);
            #pragma unroll
            for (int ni = 0; ni < 4; ni++)
                bfr[ni] = *(const bf16x8*)(&Bs[(wn*64 + ni*16 + (lane & 15))*KP + kk*32 + (lane >> 4)*8]);
            #pragma unroll
            for (int mi = 0; mi < 2; mi++)
                #pragma unroll
                for (int ni = 0; ni < 4; ni++)
                    acc[mi][ni] = __builtin_amdgcn_mfma_f32_16x16x32_bf16(af[mi], bfr[ni], acc[mi][ni], 0, 0, 0);
        }
        __syncthreads();
    }
    int cr = (lane >> 4) * 4, cc = lane & 15;
    #pragma unroll
    for (int mi = 0; mi < 2; mi++) {
        #pragma unroll
        for (int ni = 0; ni < 4; ni++) {
            int col = n0 + wn*64 + ni*16 + cc;
            float bv = bias ? bias[col] : 0.f;
            #pragma unroll
            for (int r = 0; r < 4; r++) {
                int row = m0 + wm*32 + mi*16 + cr + r;
                C[(size_t)row*ldc + col] = acc[mi][ni][r] + bv;
            }
        }
    }
}

// merged launch: blocks [0,180) = heads GEMM over all (t,b); [180,580) = encf GEMM
__launch_bounds__(256)
__global__ void heads_encf(const unsigned short* __restrict__ hb_all,
                           const unsigned short* __restrict__ Wheads,
                           const float* __restrict__ bias384, float* __restrict__ pf,
                           const float* __restrict__ enc, const unsigned short* __restrict__ Wfb,
                           const float* __restrict__ bfuse128, float* __restrict__ encf) {
    __shared__ unsigned short As[64 * 72];
    __shared__ unsigned short Bs[128 * 72];
    int id = blockIdx.x;
    if (id < 180) {
        int n0 = (id % 3) * 128, m0 = (id / 3) * 64;
        gemm_body<3, KP_G>(m0, n0, hb_all, Wheads, bias384, pf, 384, 256, As, Bs);
    } else {
        int m0 = (id - 180) * 64;
        gemm_body<1, KP_G>(m0, 0, enc, Wfb, bfuse128, encf, 128, 0, As, Bs);
    }
}

// ====== fused GRU step: (h@Whh + x@Wih) + gates; unrolled 3-deep pipeline ===
// grid (32, 8): n-tiles of 96 (2 gate-groups), m-tiles of 32. 4 waves (2m x 2n).
// 18 K-tiles of 64: tiles 0..15 from h/Wp, 16..17 from x/Wihpb — all branches
// compile-time via full unroll; loads issued 3 tiles ahead (mod-3 reg slots).
// h state kept bf16-only (hb buffers); recurrence h_prev read back from hbA.
__launch_bounds__(256)
__global__ void gru_step(const unsigned short* __restrict__ hbA,
                         const unsigned short* __restrict__ xab,
                         const unsigned short* __restrict__ Wp,
                         const unsigned short* __restrict__ Wihpb,
                         const float* __restrict__ bhhp, const float* __restrict__ bihp,
                         unsigned short* __restrict__ hb_out) {
    constexpr int KP = 72;
    __shared__ unsigned short As[2][32 * KP];
    __shared__ unsigned short Bs[2][96 * KP];
    int tid = threadIdx.x, lane = tid & 63, wid = tid >> 6;
    int wm = wid >> 1, wn = wid & 1;
    int n0 = blockIdx.x * 96, m0 = blockIdx.y * 32;
    int sr = tid >> 3, skc = tid & 7;

    const unsigned short* hA  = hbA + (size_t)(m0+sr)*KP_G + skc*8;
    const unsigned short* xA  = xab + (size_t)(m0+sr)*KP_E + skc*8;
    const unsigned short* wp0 = Wp  + (size_t)(n0+sr)*KP_G + skc*8;
    const unsigned short* wp1 = wp0 + (size_t)32*KP_G;
    const unsigned short* wp2 = wp0 + (size_t)64*KP_G;
    const unsigned short* wx0 = Wihpb + (size_t)(n0+sr)*KP_E + skc*8;
    const unsigned short* wx1 = wx0 + (size_t)32*KP_E;
    const unsigned short* wx2 = wx0 + (size_t)64*KP_E;

    auto loadT = [&](int t, bf16x8& ra, bf16x8& b0, bf16x8& b1, bf16x8& b2) {
        if (t < 16) {
            int k = t*64;
            ra = *(const bf16x8*)(hA  + k);
            b0 = *(const bf16x8*)(wp0 + k);
            b1 = *(const bf16x8*)(wp1 + k);
            b2 = *(const bf16x8*)(wp2 + k);
        } else {
            int k = (t-16)*64;
            ra = *(const bf16x8*)(xA  + k);
            b0 = *(const bf16x8*)(wx0 + k);
            b1 = *(const bf16x8*)(wx1 + k);
            b2 = *(const bf16x8*)(wx2 + k);
        }
    };
    int sA = sr*KP + skc*8;
    int sB0 = sA, sB1 = (sr+32)*KP + skc*8, sB2 = (sr+64)*KP + skc*8;

    f32x4 acc0 = {0,0,0,0}, acc1 = {0,0,0,0}, acc2 = {0,0,0,0}, acc3 = {0,0,0,0};

    bf16x8 rA[3], rB0[3], rB1[3], rB2[3];
    // prologue: tile 0 -> LDS[0]; tiles 1,2 -> reg slots 1,2
    loadT(0, rA[0], rB0[0], rB1[0], rB2[0]);
    *(bf16x8*)&As[0][sA]  = rA[0];
    *(bf16x8*)&Bs[0][sB0] = rB0[0];
    *(bf16x8*)&Bs[0][sB1] = rB1[0];
    *(bf16x8*)&Bs[0][sB2] = rB2[0];
    loadT(1, rA[1], rB0[1], rB1[1], rB2[1]);
    loadT(2, rA[2], rB0[2], rB1[2], rB2[2]);
    __syncthreads();

    int aoff  = (wm*16 + (lane & 15))*KP + (lane >> 4)*8;
    int boff0 = (wn*48 + (lane & 15))*KP + (lane >> 4)*8;
    int boff1 = boff0 + 16*KP, boff2 = boff0 + 32*KP;

    #pragma unroll
    for (int t = 0; t < 18; ++t) {
        int cur = t & 1, nxt = cur ^ 1;
        int sl = t % 3;            // slot holding tile t (already in LDS) -> reuse for t+3
        int sw = (t + 1) % 3;      // slot holding tile t+1
        if (t + 3 < 18) loadT(t+3, rA[sl], rB0[sl], rB1[sl], rB2[sl]);
        #pragma unroll
        for (int kk = 0; kk < 2; ++kk) {
            bf16x8 af = *(const bf16x8*)(&As[cur][aoff + kk*32]);
            acc0 = __builtin_amdgcn_mfma_f32_16x16x32_bf16(af, *(const bf16x8*)(&Bs[cur][boff0 + kk*32]), acc0, 0, 0, 0);
            acc1 = __builtin_amdgcn_mfma_f32_16x16x32_bf16(af, *(const bf16x8*)(&Bs[cur][boff1 + kk*32]), acc1, 0, 0, 0);
            bf16x8 b2v = *(const bf16x8*)(&Bs[cur][boff2 + kk*32]);
            if (t < 16) acc2 = __builtin_amdgcn_mfma_f32_16x16x32_bf16(af, b2v, acc2, 0, 0, 0);
            else        acc3 = __builtin_amdgcn_mfma_f32_16x16x32_bf16(af, b2v, acc3, 0, 0, 0);
        }
        if (t + 1 < 18) {
            *(bf16x8*)&As[nxt][sA]  = rA[sw];
            *(bf16x8*)&Bs[nxt][sB0] = rB0[sw];
            *(bf16x8*)&Bs[nxt][sB1] = rB1[sw];
            *(bf16x8*)&Bs[nxt][sB2] = rB2[sw];
            __syncthreads();
        }
    }

    // epilogue: lane holds gates for j = g*16 + c, rows m0 + wm*16 + (lane>>4)*4 + r
    int c = lane & 15, r0q = (lane >> 4) * 4;
    int g = n0 / 48 + wn;
    int j = g * 16 + c;
    float br = bhhp[g*48 + c]      + bihp[g*48 + c];
    float bz = bhhp[g*48 + 16 + c] + bihp[g*48 + 16 + c];
    float bn_h = bhhp[g*48 + 32 + c], bn_i = bihp[g*48 + 32 + c];
    #pragma unroll
    for (int r = 0; r < 4; r++) {
        int row = m0 + wm*16 + r0q + r;
        float rr = 1.f/(1.f + __expf(-(acc0[r] + br)));
        float zz = 1.f/(1.f + __expf(-(acc1[r] + bz)));
        float nn = tanhf(acc3[r] + bn_i + rr * (acc2[r] + bn_h));
        float hp = bf2f(hbA[(size_t)row*KP_G + j]);   // bf16 h_prev
        float h = (1.f - zz)*nn + zz*hp;
        hb_out[(size_t)row*KP_G + j] = f2bf(h);
    }
}

// ================= per-(b, 4t) outputs: encf loaded once per 4 t's ==========
// grid 1024: b = bid>>2, tq = bid&3; t = tq*4 + i. Softmax phase: one wave per t.
__launch_bounds__(256)
__global__ void output_kernel(const float* __restrict__ pf, const float* __restrict__ encf,
                              const float* __restrict__ W_copy, const float* __restrict__ b_copy,
                              float* __restrict__ out) {
    __shared__ float sf[4][100];
    __shared__ float swc[100];
    __shared__ float scp[4][104];
    int bid = blockIdx.x;
    int b = bid >> 2, tq = bid & 3;
    int t0 = tq * 4;
    int nt = min(4, Tt - t0);                 // 4,4,4,3
    int tid = threadIdx.x, lane = tid & 63, wv = tid >> 6;
    if (tid < 100) {
        swc[tid] = W_copy[tid];
        for (int i = 0; i < nt; ++i)
            sf[i][tid] = pf[(size_t)((t0 + i)*256 + b) * 384 + 256 + tid];
    }
    __syncthreads();
    const float* efb = encf + (size_t)b*Ll*128;
    float bcp = b_copy[0];
    float w0 = swc[lane];
    float w1 = (lane < 36) ? swc[lane+64] : 0.f;
    for (int l = wv; l < Ll; l += 4) {
        const float* ef = efb + (size_t)l*128;
        float e0 = ef[lane];
        float e1 = (lane < 36) ? ef[lane+64] : 0.f;
        #pragma unroll
        for (int i = 0; i < 4; ++i) {
            if (i >= nt) break;
            float pp = selu_f(sf[i][lane] + e0) * w0;
            if (lane < 36) pp += selu_f(sf[i][lane+64] + e1) * w1;
            #pragma unroll
            for (int off = 32; off > 0; off >>= 1) pp += __shfl_down(pp, off);
            if (lane == 0) scp[i][l] = pp + bcp;
        }
    }
    __syncthreads();
    // one wave per t: fully in-wave log-softmaxes
    if (wv < nt) {
        int t = t0 + wv;
        int row = t*256 + b;
        const float* pr = pf + (size_t)row * 384;
        float* ob = out + (size_t)row * OUTW;
        // pred log-softmax over 248 (= 3*64 + 56)
        float x0 = pr[lane];
        float x1 = pr[lane + 64];
        float x2 = pr[lane + 128];
        float x3 = (lane < 56) ? pr[lane + 192] : -1e30f;
        float eos = pr[247];
        float mx = fmaxf(fmaxf(x0, x1), fmaxf(x2, x3));
        #pragma unroll
        for (int off = 32; off > 0; off >>= 1) mx = fmaxf(mx, __shfl_xor(mx, off));
        float s = __expf(x0 - mx) + __expf(x1 - mx) + __expf(x2 - mx)
                + ((lane < 56) ? __expf(x3 - mx) : 0.f);
        #pragma unroll
        for (int off = 32; off > 0; off >>= 1) s += __shfl_xor(s, off);
        float lse = mx + __logf(s);
        ob[lane]       = x0 - lse;
        ob[lane + 64]  = x1 - lse;
        ob[lane + 128] = x2 - lse;
        if (lane < 56) ob[lane + 192] = x3 - lse;
        // copy log-softmax over 101 (= 64 + 36 + eos)
        float y0 = scp[wv][lane];
        float y1 = (lane < 36) ? scp[wv][lane + 64] : -1e30f;
        float my = fmaxf(y0, fmaxf(y1, eos));
        #pragma unroll
        for (int off = 32; off > 0; off >>= 1) my = fmaxf(my, __shfl_xor(my, off));
        float sy = __expf(y0 - my) + ((lane < 36) ? __expf(y1 - my) : 0.f)
                 + ((lane == 0) ? __expf(eos - my) : 0.f);
        #pragma unroll
        for (int off = 32; off > 0; off >>= 1) sy += __shfl_xor(sy, off);
        float lsey = my + __logf(sy);
        ob[248 + lane] = y0 - lsey;
        if (lane < 36) ob[248 + 64 + lane] = y1 - lsey;
        if (lane == 0) ob[248 + 100] = eos - lsey;
    }
}

// ============================================================================
extern "C" void kernel_launch(void* const* d_in, const int* in_sizes, int n_in,
                              void* d_out, int out_size, void* d_ws, size_t ws_size,
                              hipStream_t stream) {
    const float* emb    = (const float*)d_in[0];
    const float* enc    = (const float*)d_in[1];
    const float* conv   = (const float*)d_in[2];
    const float* h0     = (const float*)d_in[3];
    const float* W_attn = (const float*)d_in[4];
    const float* W_comb = (const float*)d_in[6];
    const float* b_comb = (const float*)d_in[7];
    const float* W_ih   = (const float*)d_in[8];
    const float* W_hh   = (const float*)d_in[9];
    const float* b_ih   = (const float*)d_in[10];
    const float* b_hh   = (const float*)d_in[11];
    const float* W_eos  = (const float*)d_in[12];
    const float* b_eos  = (const float*)d_in[13];
    const float* W_pred = (const float*)d_in[14];
    const float* b_pred = (const float*)d_in[15];
    const float* W_fuse = (const float*)d_in[16];
    const float* b_fuse = (const float*)d_in[17];
    const float* W_copy = (const float*)d_in[18];
    const float* b_copy = (const float*)d_in[19];
    float* out = (float*)d_out;

    char* p = (char*)d_ws;
    auto alloc = [&](size_t bytes) -> void* {
        void* r = (void*)p; p += (bytes + 255) & ~(size_t)255; return r;
    };
    float* pss    = (float*)alloc((size_t)Bb*12*4);
    float* pc     = (float*)alloc((size_t)Bb*12*1000*4);
    unsigned short* x_allb = (unsigned short*)alloc((size_t)Tt*Bb*KP_E*2);
    float* encf   = (float*)alloc((size_t)Bb*Ll*128*4);
    unsigned short* Wp     = (unsigned short*)alloc((size_t)NCP*KP_G*2);
    unsigned short* Wihpb  = (unsigned short*)alloc((size_t)NCP*KP_E*2);
    unsigned short* Wheads = (unsigned short*)alloc((size_t)384*KP_G*2);
    unsigned short* Wfb    = (unsigned short*)alloc((size_t)128*KP_G*2);
    float* bhhp     = (float*)alloc(NCP*4);
    float* bihp     = (float*)alloc(NCP*4);
    float* bias384  = (float*)alloc(384*4);
    float* bfuse128 = (float*)alloc(128*4);
    unsigned short* h0b    = (unsigned short*)alloc((size_t)Bb*KP_G*2);
    unsigned short* hb_all = (unsigned short*)alloc((size_t)Tt*Bb*KP_G*2);
    float* pf = (float*)alloc((size_t)Tt*Bb*384*4);

    // ---- attention + ALL packing in ONE dispatch (independent work overlaps) ----
    attn_pack<<<3072 + 5260, 256, 0, stream>>>(
        enc, conv, W_attn + Hh, pss, pc,
        W_hh, W_ih, W_pred, W_fuse, h0, b_hh, b_ih, b_pred, b_eos, W_eos, b_fuse,
        Wp, Wihpb, Wheads, Wfb, h0b, bhhp, bihp, bias384, bfuse128);
    fused_ctx<<<Bb, 256, 0, stream>>>(pss, pc, W_comb, b_comb, emb, x_allb);

    // ---- serial GRU: 3-deep-pipelined LDS kernel per step (bf16-only h) ----
    const unsigned short* hbprev = h0b;
    for (int t = 0; t < Tt; ++t) {
        unsigned short* hbnext = hb_all + (size_t)t*Bb*KP_G;
        gru_step<<<dim3(32, 8), 256, 0, stream>>>(hbprev, x_allb + (size_t)t*Bb*KP_E,
                                                  Wp, Wihpb, bhhp, bihp, hbnext);
        hbprev = hbnext;
    }

    // ---- heads GEMM (t,b batched) + encf GEMM in ONE launch (580 blocks) ----
    heads_encf<<<580, 256, 0, stream>>>(hb_all, Wheads, bias384, pf, enc, Wfb, bfuse128, encf);
    output_kernel<<<1024, 256, 0, stream>>>(pf, encf, W_copy, b_copy, out);
}